// Round 1
// 782.820 us; speedup vs baseline: 1.0995x; 1.0995x over previous
//
#include <hip/hip_runtime.h>
#include <math.h>

// Problem dims
#define NB   64      // batch B
#define NN   256     // tokens N
#define HSS  768     // H_S
#define HTT  1024    // H_T
#define ROWS (NB*NN) // 16384
#define C2LOG 14.426950408889634f  // 10 * log2(e)

typedef unsigned short u16;
typedef __attribute__((ext_vector_type(8))) short bf16x8;
typedef __attribute__((ext_vector_type(4))) float f32x4;

// swizzled LDS index for K[r][c] (256 cols): chunk rotation, 8-u16 granularity
#define LIDX(r,c) (((r)<<8) + (((((c)>>3) + (r)) & 31)<<3) + ((c)&7))
// swizzled LDS index for E[r][c] (128 cols, 16 chunks of 8)
#define EIDX(r,c) (((r)<<7) + (((((c)>>3) + (r)) & 15)<<3) + ((c)&7))

// ---------------- workspace layout (float offsets) ----------------
static const size_t OFF_ACC   = 0;                          // 16 floats
static const size_t OFF_SQ128 = 16;
static const size_t OFF_SP128 = OFF_SQ128 + 64*128;
static const size_t OFF_TQ128 = OFF_SP128 + 64*128;
static const size_t OFF_TP128 = OFF_TQ128 + 64*128;
static const size_t OFF_SQ768 = OFF_TP128 + 64*128;
static const size_t OFF_SP768 = OFF_SQ768 + 64*768;
static const size_t OFF_DS    = OFF_SP768 + 64*768;         // 128*128
static const size_t OFF_DT    = OFF_DS + 128*128;
static const size_t OFF_CS    = OFF_DT + 128*128;           // 2*B*N*N f32
static const size_t OFF_MBF   = OFF_CS  + (size_t)2*NB*NN*NN;     // 2*B*N*N bf16
static const size_t OFF_ZS_BF = OFF_MBF + (size_t)NB*NN*NN;       // 16384x768 bf16
static const size_t OFF_ZT_BF = OFF_ZS_BF + (size_t)ROWS*HSS/2;   // 16384x1024 bf16
static const size_t OFF_WT_BF = OFF_ZT_BF + (size_t)ROWS*HTT/2;   // 1024x768 bf16
static const size_t OFF_ZSP_BF= OFF_WT_BF + (size_t)HTT*HSS/2;    // 16384x1024 bf16
static const size_t OFF_GN_BF = OFF_ZSP_BF+ (size_t)ROWS*HTT/2;   // 2*B*N*N bf16
static const size_t OFF_CT_BF = OFF_GN_BF + (size_t)NB*NN*NN;     // 2*B*N*N bf16
static const size_t OFF_T_BF  = OFF_ZS_BF;                  // ALIAS: ZS dead after cost GEMMs
static const size_t OFF_NS    = OFF_CT_BF + (size_t)NB*NN*NN;
static const size_t OFF_NT    = OFF_NS + ROWS;
static const size_t OFF_NSP   = OFF_NT + ROWS;
static const size_t OFF_MU    = OFF_NSP + ROWS;             // 2*ROWS (linear)
static const size_t OFF_NU    = OFF_MU + 2*ROWS;            // 2*ROWS (linear)

// acc: 0=contrastive 1=ds_sum 2=dt_sum 3=dist_huber 4=angle_huber 5=feat 6=struct

// ---------------- helpers ----------------
__device__ __forceinline__ float wred_sum(float v){
  #pragma unroll
  for(int o=32;o>0;o>>=1) v += __shfl_xor(v,o,64);
  return v;
}
__device__ __forceinline__ float wred_max(float v){
  #pragma unroll
  for(int o=32;o>0;o>>=1) v = fmaxf(v, __shfl_xor(v,o,64));
  return v;
}
__device__ __forceinline__ u16 f2bf(float f){
  unsigned u = __float_as_uint(f);
  unsigned r = (u + 0x7fffu + ((u>>16)&1u)) >> 16;
  return (u16)r;
}
__device__ __forceinline__ float bf2f(u16 h){
  return __uint_as_float(((unsigned)h)<<16);
}

// ---------------- Part A kernels ----------------
__global__ __launch_bounds__(256) void k_l2norm_rows(const float* __restrict__ in,
    float* __restrict__ out, int k_in, int k_use){
  int r = blockIdx.x;
  const float* row = in + (size_t)r*k_in;
  float ss = 0.f;
  for(int d=threadIdx.x; d<k_use; d+=256){ float x=row[d]; ss += x*x; }
  ss = wred_sum(ss);
  __shared__ float sm[4];
  if((threadIdx.x&63)==0) sm[threadIdx.x>>6]=ss;
  __syncthreads();
  float tot = sm[0]+sm[1]+sm[2]+sm[3];
  float inv = 1.f / fmaxf(sqrtf(tot), 1e-12f);
  for(int d=threadIdx.x; d<k_use; d+=256) out[(size_t)r*k_use + d] = row[d]*inv;
}

// contrastive: one block per row i; 8 waves split the dot-product dim;
// wave 0 does the 64-wide softmax. float4 loads; data is L2-resident.
__global__ __launch_bounds__(512) void k_contrastive(const float* __restrict__ q,
    const float* __restrict__ p, int dim, float weight, float* __restrict__ acc){
  int i = blockIdx.x;
  int j = threadIdx.x & 63;
  int part = threadIdx.x >> 6;           // 0..7
  const float* qi = q + (size_t)i*dim;
  const float* pj = p + (size_t)j*dim;
  int seg = dim >> 3;                    // 96 (dim=768) or 16 (dim=128)
  int d0 = part*seg;
  float dot = 0.f;
  for(int d=d0; d<d0+seg; d+=4){
    float4 a = *(const float4*)(qi+d);
    float4 b = *(const float4*)(pj+d);
    dot = fmaf(a.x,b.x,dot);
    dot = fmaf(a.y,b.y,dot);
    dot = fmaf(a.z,b.z,dot);
    dot = fmaf(a.w,b.w,dot);
  }
  __shared__ float sm[8][64];
  sm[part][j] = dot;
  __syncthreads();
  if(part==0){
    float s = 0.f;
    #pragma unroll
    for(int k=0;k<8;k++) s += sm[k][j];
    s = s / 0.07f;
    float mx = wred_max(s);
    float e = expf(s - mx);
    float Z = wred_sum(e);
    float logZ = mx + logf(Z);
    float diag = __shfl(s, i, 64);
    if(j==0) atomicAdd(acc+0, weight*(logZ - diag)*(1.f/64.f));
  }
}

__global__ __launch_bounds__(128) void k_gram_ds(const float* __restrict__ sb,
    const float* __restrict__ tb, float* __restrict__ ds, float* __restrict__ dt,
    float* __restrict__ acc){
  int r = blockIdx.x, c = threadIdx.x;
  const float* sr = sb + r*128; const float* sc = sb + c*128;
  const float* tr = tb + r*128; const float* tc = tb + c*128;
  float dot_s=0,ssr=0,ssc=0,dot_t=0,tsr=0,tsc=0;
  for(int d=0; d<128; d++){
    float a=sr[d], b=sc[d]; dot_s += a*b; ssr += a*a; ssc += b*b;
    float at=tr[d], bt=tc[d]; dot_t += at*bt; tsr += at*at; tsc += bt*bt;
  }
  float dv = ssr + ssc - 2.f*dot_s;
  float tv = tsr + tsc - 2.f*dot_t;
  ds[r*128+c] = dv; dt[r*128+c] = tv;
  float ms = (c>r)? dv : 0.f;
  float mt = (c>r)? tv : 0.f;
  ms = wred_sum(ms); mt = wred_sum(mt);
  __shared__ float sm[2][2];
  if((threadIdx.x&63)==0){ sm[0][threadIdx.x>>6]=ms; sm[1][threadIdx.x>>6]=mt; }
  __syncthreads();
  if(threadIdx.x==0){ atomicAdd(acc+1, sm[0][0]+sm[0][1]); atomicAdd(acc+2, sm[1][0]+sm[1][1]); }
}

__global__ __launch_bounds__(128) void k_rkd_dist(const float* __restrict__ ds,
    const float* __restrict__ dt, float* __restrict__ acc){
  int r=blockIdx.x, c=threadIdx.x;
  float mean_s = acc[1]*(1.f/8128.f) + 1e-8f;
  float mean_t = acc[2]*(1.f/8128.f) + 1e-8f;
  float h=0.f;
  if(c>r){
    float diff = ds[r*128+c]/mean_s - dt[r*128+c]/mean_t;
    float a = fabsf(diff);
    h = (a<1.f)? 0.5f*a*a : a-0.5f;
  }
  h = wred_sum(h);
  __shared__ float sm[2];
  if((threadIdx.x&63)==0) sm[threadIdx.x>>6]=h;
  __syncthreads();
  if(threadIdx.x==0) atomicAdd(acc+3, sm[0]+sm[1]);
}

// ---- RKD angle via MFMA: psi = E E^T, E in bf16 LDS, huber fused ----
// grid (j, colhalf) = 256 blocks x 256 thr. 64KB dynamic LDS: Es,Et (128x128 bf16).
#define RKD_LDS 65536
__global__ __launch_bounds__(256, 1) void k_rkd_angle_mfma(
    const float* __restrict__ sb, const float* __restrict__ tb,
    float* __restrict__ accp)
{
  extern __shared__ u16 eSh[];
  u16* Es = eSh;
  u16* Et = eSh + 128*128;
  const int j    = blockIdx.x >> 1;
  const int half = blockIdx.x & 1;
  const int tid = threadIdx.x;
  // stage e-vectors: 2 threads per row (i = tid/2, h = tid&1 -> 64 elems)
  {
    const int i = tid >> 1, h = tid & 1;
    #pragma unroll
    for(int which=0; which<2; which++){
      const float* xb = which ? tb : sb;
      u16* E = which ? Et : Es;
      const float* xj = xb + j*128 + h*64;
      const float* xi = xb + i*128 + h*64;
      float ss = 0.f;
      #pragma unroll
      for(int d4=0; d4<16; d4++){
        float4 a = *(const float4*)(xj + d4*4);
        float4 b = *(const float4*)(xi + d4*4);
        float d0=a.x-b.x, d1=a.y-b.y, d2=a.z-b.z, d3=a.w-b.w;
        ss += d0*d0+d1*d1+d2*d2+d3*d3;
      }
      ss += __shfl_xor(ss, 1, 64);
      float inv = (i==j) ? 0.f : 1.f/(sqrtf(ss)+1e-8f);
      #pragma unroll
      for(int d4=0; d4<16; d4++){
        float4 a = *(const float4*)(xj + d4*4);
        float4 b = *(const float4*)(xi + d4*4);
        int c = h*64 + d4*4;
        E[EIDX(i,c+0)] = f2bf((a.x-b.x)*inv);
        E[EIDX(i,c+1)] = f2bf((a.y-b.y)*inv);
        E[EIDX(i,c+2)] = f2bf((a.z-b.z)*inv);
        E[EIDX(i,c+3)] = f2bf((a.w-b.w)*inv);
      }
    }
  }
  __syncthreads();
  // MFMA: wave w computes rows [w*32,w*32+32) x cols [half*64, half*64+64)
  const int w = tid >> 6, lane = tid & 63;
  const int q = lane >> 4, loc = lane & 15;
  float hsum = 0.f;
  #pragma unroll
  for(int ni=0; ni<4; ni++){
    const int cb = half*64 + ni*16;
    #pragma unroll
    for(int mi=0; mi<2; mi++){
      const int rb = w*32 + mi*16;
      f32x4 as_ = {0.f,0.f,0.f,0.f}, at_ = {0.f,0.f,0.f,0.f};
      #pragma unroll
      for(int k0=0; k0<128; k0+=32){
        int ra = rb + loc, rbn = cb + loc;
        int ca = k0 + q*8;
        bf16x8 aS = *(const bf16x8*)(Es + EIDX(ra, ca));
        bf16x8 bS = *(const bf16x8*)(Es + EIDX(rbn, ca));
        bf16x8 aT = *(const bf16x8*)(Et + EIDX(ra, ca));
        bf16x8 bT = *(const bf16x8*)(Et + EIDX(rbn, ca));
        as_ = __builtin_amdgcn_mfma_f32_16x16x32_bf16(aS, bS, as_, 0,0,0);
        at_ = __builtin_amdgcn_mfma_f32_16x16x32_bf16(aT, bT, at_, 0,0,0);
      }
      // huber on diff; D[row][col]: row = rb + q*4 + jj, col = cb + loc
      #pragma unroll
      for(int jj=0; jj<4; jj++){
        int row = rb + q*4 + jj, col = cb + loc;
        if(row != col){
          float d = as_[jj] - at_[jj];
          float a = fabsf(d);
          hsum += (a < 1.f) ? 0.5f*a*a : a - 0.5f;
        }
      }
    }
  }
  hsum = wred_sum(hsum);
  __syncthreads();               // eSh reads done; reuse as scratch
  float* red = (float*)eSh;
  if(lane==0) red[w] = hsum;
  __syncthreads();
  if(tid==0) atomicAdd(accp+4, red[0]+red[1]+red[2]+red[3]);
}

// ---------------- Part B: convert+norm / saliency ----------------
__global__ __launch_bounds__(256) void k_cvt_norm(const float* __restrict__ in,
    u16* __restrict__ out, float* __restrict__ nrm, int K){
  int r = blockIdx.x;
  const float* row = in + (size_t)r*K;
  u16* orow = out + (size_t)r*K;
  float ss=0.f;
  for(int d=threadIdx.x; d<K; d+=256){ float x=row[d]; ss+=x*x; orow[d]=f2bf(x); }
  ss = wred_sum(ss);
  __shared__ float sm[4];
  if((threadIdx.x&63)==0) sm[threadIdx.x>>6]=ss;
  __syncthreads();
  if(threadIdx.x==0) nrm[r] = sqrtf(sm[0]+sm[1]+sm[2]+sm[3]);
}

__global__ __launch_bounds__(256) void k_row_norm_bf16(const u16* __restrict__ z,
    float* __restrict__ nrm, int K){
  int r = blockIdx.x;
  const u16* row = z + (size_t)r*K;
  float ss=0.f;
  for(int d=threadIdx.x; d<K; d+=256){ float x=bf2f(row[d]); ss+=x*x; }
  ss = wred_sum(ss);
  __shared__ float sm[4];
  if((threadIdx.x&63)==0) sm[threadIdx.x>>6]=ss;
  __syncthreads();
  if(threadIdx.x==0) nrm[r] = sqrtf(sm[0]+sm[1]+sm[2]+sm[3]);
}

// W (HSS x HTT) f32 -> Wt (HTT x HSS) bf16
__global__ void k_wt(const float* __restrict__ W, u16* __restrict__ Wt){
  __shared__ float t[32][33];
  int k0 = blockIdx.y*32, n0 = blockIdx.x*32;
  int tx = threadIdx.x, ty = threadIdx.y;
  for(int r=0;r<32;r+=8) t[ty+r][tx] = W[(size_t)(k0+ty+r)*HTT + n0+tx];
  __syncthreads();
  for(int r=0;r<32;r+=8) Wt[(size_t)(n0+ty+r)*HSS + k0+tx] = f2bf(t[tx][ty+r]);
}

// softmax over N (linear output)
__global__ __launch_bounds__(256) void k_saliency(const float* __restrict__ nrm,
    float* __restrict__ out){
  int b = blockIdx.x, n = threadIdx.x;
  float x = nrm[b*NN+n];
  float mx = wred_max(x);
  __shared__ float sm[4], sm2[4];
  if((n&63)==0) sm[n>>6]=mx;
  __syncthreads();
  mx = fmaxf(fmaxf(sm[0],sm[1]),fmaxf(sm[2],sm[3]));
  float e = expf(x-mx);
  float s = wred_sum(e);
  if((n&63)==0) sm2[n>>6]=s;
  __syncthreads();
  s = sm2[0]+sm2[1]+sm2[2]+sm2[3];
  out[b*NN+n] = e/s;
}

// ---------------- MFMA GEMM (NT form) ----------------
enum { MODE_PROJ=0, MODE_COST=1, MODE_PLAIN=2, MODE_STRUCT=3 };

template<int MODE>
__global__ __launch_bounds__(256) void k_mfma(
    const u16* __restrict__ A, int lda, long bA,
    const u16* __restrict__ B, int ldb, long bB,
    int K,
    float* __restrict__ outF, u16* __restrict__ outB, int ldo, long bO,
    const float* __restrict__ nx, const float* __restrict__ ny,
    const float* __restrict__ bias,
    const float* __restrict__ Cs, const float* __restrict__ mu,
    float* __restrict__ accp)
{
  __shared__ u16 As[128*32];
  __shared__ u16 Bs[128*32];
  __shared__ float red[4];
  int b = blockIdx.z;
  const u16* Ab = A + (size_t)b*bA;
  const u16* Bb = B + (size_t)b*bB;
  int tid = threadIdx.x;
  int lane = tid & 63, w = tid >> 6;
  int m0 = blockIdx.y*128, n0 = blockIdx.x*128;
  int row_off = (w>>1)*64, col_off = (w&1)*64;
  int q = lane>>4, loc = lane&15;
  f32x4 acc[4][4] = {};
  int srow = tid >> 2;
  int skc  = tid & 3;

  for(int k0=0;k0<K;k0+=32){
    #pragma unroll
    for(int h=0;h<2;h++){
      int row = srow + h*64;
      int slot = skc ^ ((row>>1)&3);
      uint4 av = *(const uint4*)(Ab + (size_t)(m0+row)*lda + k0 + skc*8);
      uint4 bv = *(const uint4*)(Bb + (size_t)(n0+row)*ldb + k0 + skc*8);
      *(uint4*)(As + row*32 + slot*8) = av;
      *(uint4*)(Bs + row*32 + slot*8) = bv;
    }
    __syncthreads();
    bf16x8 af[4], bfr[4];
    #pragma unroll
    for(int mi=0;mi<4;mi++){
      int r = row_off + mi*16 + loc;
      int slot = q ^ ((r>>1)&3);
      af[mi] = *(const bf16x8*)(As + r*32 + slot*8);
    }
    #pragma unroll
    for(int ni=0;ni<4;ni++){
      int r = col_off + ni*16 + loc;
      int slot = q ^ ((r>>1)&3);
      bfr[ni] = *(const bf16x8*)(Bs + r*32 + slot*8);
    }
    #pragma unroll
    for(int mi=0;mi<4;mi++)
      #pragma unroll
      for(int ni=0;ni<4;ni++)
        acc[mi][ni] = __builtin_amdgcn_mfma_f32_16x16x32_bf16(af[mi], bfr[ni], acc[mi][ni], 0,0,0);
    __syncthreads();
  }

  float* outFb = outF ? outF + (size_t)b*bO : nullptr;
  u16*   outBb = outB ? outB + (size_t)b*bO : nullptr;
  const float* nxb = nx ? nx + (size_t)b*NN : nullptr;
  const float* nyb = ny ? ny + (size_t)b*NN : nullptr;
  const float* Cb  = (MODE==MODE_STRUCT) ? Cs + (size_t)b*bO : nullptr;
  const float* mb  = (MODE==MODE_STRUCT) ? mu + (size_t)b*NN : nullptr;
  float lsum = 0.f;
  #pragma unroll
  for(int mi=0;mi<4;mi++){
    #pragma unroll
    for(int j=0;j<4;j++){
      int row = m0 + row_off + mi*16 + q*4 + j;
      float ir = 0.f, mr = 0.f;
      if(MODE==MODE_COST)   ir = 1.f/fmaxf(nxb[row],1e-12f);
      if(MODE==MODE_STRUCT) mr = mb[row];
      #pragma unroll
      for(int ni=0;ni<4;ni++){
        int col = n0 + col_off + ni*16 + loc;
        float v = acc[mi][ni][j];
        if(MODE==MODE_PROJ){
          v += bias[col];
          outBb[(size_t)row*ldo + col] = f2bf(v);
        } else if(MODE==MODE_COST){
          float ic = 1.f/fmaxf(nyb[col],1e-12f);
          v = 1.f - v*ir*ic;
          if(outFb) outFb[(size_t)row*ldo + col] = v;
          if(outBb) outBb[(size_t)row*ldo + col] = f2bf(v);
        } else if(MODE==MODE_PLAIN){
          outBb[(size_t)row*ldo + col] = f2bf(v);
        } else {
          float d = Cb[(size_t)row*ldo + col] - v;
          lsum += d*d*mr*mb[col];
        }
      }
    }
  }
  if(MODE==MODE_STRUCT){
    lsum = wred_sum(lsum);
    if(lane==0) red[w] = lsum;
    __syncthreads();
    if(tid==0) atomicAdd(accp+6, red[0]+red[1]+red[2]+red[3]);
  }
}

// ---------------- fused Sinkhorn: multiplicative domain, K in LDS ----------------
#define SINK_DYN_LDS 131072
__global__ __launch_bounds__(1024, 1) void k_sinkhorn_fused(
    const u16* __restrict__ Mbf, const float* __restrict__ muL,
    const float* __restrict__ nuL, u16* __restrict__ Gn, float* __restrict__ accp)
{
  extern __shared__ u16 Ks[];                      // 256x256 bf16, swizzled
  __shared__ __align__(16) float part[4096];       // reduction scratch
  __shared__ __align__(16) float su[NN], sv[NN], smu[NN], snu[NN];
  __shared__ float red[16];

  const int b = blockIdx.x;
  const int t = threadIdx.x;
  const u16* Mb = Mbf + (size_t)b*NN*NN;

  #pragma unroll
  for(int i=0;i<16;i++){
    int e = (i*1024 + t)*4;
    int r = e>>8, c = e&255;
    ushort4 mv = *(const ushort4*)(Mb + e);
    ushort4 o;
    o.x = f2bf(exp2f(-C2LOG*bf2f(mv.x)));
    o.y = f2bf(exp2f(-C2LOG*bf2f(mv.y)));
    o.z = f2bf(exp2f(-C2LOG*bf2f(mv.z)));
    o.w = f2bf(exp2f(-C2LOG*bf2f(mv.w)));
    *(ushort4*)(Ks + LIDX(r,c)) = o;
  }
  if(t < NN){
    smu[t] = muL[(size_t)b*NN+t] + 1e-8f;
    snu[t] = nuL[(size_t)b*NN+t] + 1e-8f;
    sv[t] = 1.f;
  }
  __syncthreads();

  const int r_ = t & 255, p_ = t >> 8;
  const int w = t>>6, l = t&63;

  for(int it=0; it<20; it++){
    {
      float sacc = 0.f;
      #pragma unroll
      for(int jj=0;jj<8;jj++){
        int c0 = p_*64 + jj*8;
        uint4 kv = *(const uint4*)(Ks + LIDX(r_, c0));
        float4 va = *(const float4*)(sv + c0);
        float4 vb = *(const float4*)(sv + c0 + 4);
        sacc += __uint_as_float(kv.x<<16)          * va.x;
        sacc += __uint_as_float(kv.x & 0xffff0000u)* va.y;
        sacc += __uint_as_float(kv.y<<16)          * va.z;
        sacc += __uint_as_float(kv.y & 0xffff0000u)* va.w;
        sacc += __uint_as_float(kv.z<<16)          * vb.x;
        sacc += __uint_as_float(kv.z & 0xffff0000u)* vb.y;
        sacc += __uint_as_float(kv.w<<16)          * vb.z;
        sacc += __uint_as_float(kv.w & 0xffff0000u)* vb.w;
      }
      part[t] = sacc;
    }
    __syncthreads();
    if(t < NN){
      float S = part[t] + part[256+t] + part[512+t] + part[768+t];
      su[t] = smu[t] / S;
    }
    __syncthreads();
    {
      float cs0=0.f,cs1=0.f,cs2=0.f,cs3=0.f;
      #pragma unroll
      for(int rr=0;rr<16;rr++){
        int r = w*16 + rr;
        ushort4 kv = *(const ushort4*)(Ks + LIDX(r, l*4));
        float ur = su[r];
        cs0 = fmaf(bf2f(kv.x), ur, cs0);
        cs1 = fmaf(bf2f(kv.y), ur, cs1);
        cs2 = fmaf(bf2f(kv.z), ur, cs2);
        cs3 = fmaf(bf2f(kv.w), ur, cs3);
      }
      float4 o; o.x=cs0; o.y=cs1; o.z=cs2; o.w=cs3;
      *(float4*)(part + w*256 + l*4) = o;
    }
    __syncthreads();
    if(t < NN){
      float S = 0.f;
      #pragma unroll
      for(int ww=0;ww<16;ww++) S += part[ww*256 + t];
      sv[t] = snu[t] / S;
    }
    __syncthreads();
  }

  {
    float sacc = 0.f;
    #pragma unroll
    for(int jj=0;jj<8;jj++){
      int c0 = p_*64 + jj*8;
      uint4 kv = *(const uint4*)(Ks + LIDX(r_, c0));
      float4 va = *(const float4*)(sv + c0);
      float4 vb = *(const float4*)(sv + c0 + 4);
      sacc += __uint_as_float(kv.x<<16)          * va.x;
      sacc += __uint_as_float(kv.x & 0xffff0000u)* va.y;
      sacc += __uint_as_float(kv.y<<16)          * va.z;
      sacc += __uint_as_float(kv.y & 0xffff0000u)* va.w;
      sacc += __uint_as_float(kv.z<<16)          * vb.x;
      sacc += __uint_as_float(kv.z & 0xffff0000u)* vb.y;
      sacc += __uint_as_float(kv.w<<16)          * vb.z;
      sacc += __uint_as_float(kv.w & 0xffff0000u)* vb.w;
    }
    part[t] = sacc;
  }
  __syncthreads();
  if(t < NN){
    float S = part[t] + part[256+t] + part[512+t] + part[768+t];
    smu[t] = 1.f / (su[t]*S + 1e-8f);
  }
  __syncthreads();

  u16* Gb = Gn + (size_t)b*NN*NN;
  const float IC = -1.f/C2LOG;
  float v0 = sv[l*4+0], v1 = sv[l*4+1], v2 = sv[l*4+2], v3 = sv[l*4+3];
  float fl = 0.f;
  for(int rr=0;rr<16;rr++){
    int r = w*16 + rr;
    ushort4 kv = *(const ushort4*)(Ks + LIDX(r, l*4));
    float k0=bf2f(kv.x), k1=bf2f(kv.y), k2=bf2f(kv.z), k3=bf2f(kv.w);
    float ur = su[r], inv = smu[r];
    float g0=ur*k0*v0, g1=ur*k1*v1, g2=ur*k2*v2, g3=ur*k3*v3;
    fl += g0*(__log2f(k0)*IC) + g1*(__log2f(k1)*IC)
        + g2*(__log2f(k2)*IC) + g3*(__log2f(k3)*IC);
    ushort4 o;
    o.x=f2bf(g0*inv); o.y=f2bf(g1*inv); o.z=f2bf(g2*inv); o.w=f2bf(g3*inv);
    *(ushort4*)(Gb + (size_t)r*NN + l*4) = o;
  }
  fl = wred_sum(fl);
  if(l==0) red[w] = fl;
  __syncthreads();
  if(t==0){
    float s=0.f;
    #pragma unroll
    for(int i=0;i<16;i++) s+=red[i];
    atomicAdd(accp+5, s);
  }
}

__global__ void k_final(const float* __restrict__ acc, float* __restrict__ out){
  out[0] = acc[0]
         + 20.f*acc[3]*(1.f/8128.f)
         + 40.f*acc[4]*(1.f/2048256.f)
         + 0.25f*(acc[5]+acc[6])*(1.f/64.f);
}

// ---------------- host ----------------
extern "C" void kernel_launch(void* const* d_in, const int* in_sizes, int n_in,
                              void* d_out, int out_size, void* d_ws, size_t ws_size,
                              hipStream_t stream) {
  const float* s_q_reps   = (const float*)d_in[0];
  const float* s_p_reps   = (const float*)d_in[1];
  const float* t_q_reps   = (const float*)d_in[2];
  const float* t_p_reps   = (const float*)d_in[3];
  const float* s_q_states = (const float*)d_in[4];
  const float* s_p_states = (const float*)d_in[5];
  const float* t_q_states = (const float*)d_in[6];
  const float* t_p_states = (const float*)d_in[7];
  const float* proj_w     = (const float*)d_in[8];
  const float* proj_b     = (const float*)d_in[9];
  float* ws = (float*)d_ws;
  float* acc = ws + OFF_ACC;
  u16* M_BF   = (u16*)(ws + OFF_MBF);
  u16* ZS_BF  = (u16*)(ws + OFF_ZS_BF);
  u16* ZT_BF  = (u16*)(ws + OFF_ZT_BF);
  u16* WT_BF  = (u16*)(ws + OFF_WT_BF);
  u16* ZSP_BF = (u16*)(ws + OFF_ZSP_BF);
  u16* GN_BF  = (u16*)(ws + OFF_GN_BF);
  u16* CT_BF  = (u16*)(ws + OFF_CT_BF);
  u16* T_BF   = (u16*)(ws + OFF_T_BF);

  hipFuncSetAttribute(reinterpret_cast<const void*>(k_sinkhorn_fused),
                      hipFuncAttributeMaxDynamicSharedMemorySize, SINK_DYN_LDS);
  hipFuncSetAttribute(reinterpret_cast<const void*>(k_rkd_angle_mfma),
                      hipFuncAttributeMaxDynamicSharedMemorySize, RKD_LDS);

  hipMemsetAsync(acc, 0, 16*sizeof(float), stream);

  // ---- Part A ----
  k_l2norm_rows<<<64,256,0,stream>>>(s_q_reps, ws+OFF_SQ128, 768, 128);
  k_l2norm_rows<<<64,256,0,stream>>>(s_p_reps, ws+OFF_SP128, 768, 128);
  k_l2norm_rows<<<64,256,0,stream>>>(t_q_reps, ws+OFF_TQ128, 768, 128);
  k_l2norm_rows<<<64,256,0,stream>>>(t_p_reps, ws+OFF_TP128, 768, 128);
  k_l2norm_rows<<<64,256,0,stream>>>(s_q_reps, ws+OFF_SQ768, 768, 768);
  k_l2norm_rows<<<64,256,0,stream>>>(s_p_reps, ws+OFF_SP768, 768, 768);
  k_contrastive<<<64,512,0,stream>>>(ws+OFF_SQ128, ws+OFF_SP128, 128, 1.0f, acc);
  k_contrastive<<<64,512,0,stream>>>(ws+OFF_SQ768, ws+OFF_SP768, 768, 2.0f, acc);
  k_gram_ds<<<128,128,0,stream>>>(ws+OFF_SQ128, ws+OFF_TQ128, ws+OFF_DS, ws+OFF_DT, acc);
  k_rkd_dist<<<128,128,0,stream>>>(ws+OFF_DS, ws+OFF_DT, acc);
  k_rkd_angle_mfma<<<256,256,RKD_LDS,stream>>>(ws+OFF_SQ128, ws+OFF_TQ128, acc);

  k_wt<<<dim3(HTT/32, HSS/32),dim3(32,8),0,stream>>>(proj_w, WT_BF);

  // ---- Part B phase 1: per-pass GEMMs into doubled buffers ----
  for(int pass=0; pass<2; pass++){
    const float* zs = pass ? s_p_states : s_q_states;
    const float* zt = pass ? t_p_states : t_q_states;
    size_t po  = (size_t)pass*NB*NN*NN;
    size_t pr  = (size_t)pass*ROWS;
    k_cvt_norm<<<ROWS,256,0,stream>>>(zs, ZS_BF, ws+OFF_NS, HSS);
    k_cvt_norm<<<ROWS,256,0,stream>>>(zt, ZT_BF, ws+OFF_NT, HTT);
    k_saliency<<<NB,256,0,stream>>>(ws+OFF_NS, ws+OFF_MU+pr);
    k_saliency<<<NB,256,0,stream>>>(ws+OFF_NT, ws+OFF_NU+pr);
    k_mfma<MODE_PROJ><<<dim3(HTT/128, ROWS/128, 1),256,0,stream>>>(
        ZS_BF, HSS, 0, WT_BF, HSS, 0, HSS,
        nullptr, ZSP_BF, HTT, 0,
        nullptr, nullptr, proj_b, nullptr, nullptr, nullptr);
    k_row_norm_bf16<<<ROWS,256,0,stream>>>(ZSP_BF, ws+OFF_NSP, HTT);
    // C_s (f32)
    k_mfma<MODE_COST><<<dim3(2,2,NB),256,0,stream>>>(
        ZS_BF, HSS, (long)NN*HSS, ZS_BF, HSS, (long)NN*HSS, HSS,
        ws+OFF_CS+po, nullptr, NN, (long)NN*NN,
        ws+OFF_NS, ws+OFF_NS, nullptr, nullptr, nullptr, nullptr);
    // C_t (bf16)
    k_mfma<MODE_COST><<<dim3(2,2,NB),256,0,stream>>>(
        ZT_BF, HTT, (long)NN*HTT, ZT_BF, HTT, (long)NN*HTT, HTT,
        nullptr, CT_BF+po, NN, (long)NN*NN,
        ws+OFF_NT, ws+OFF_NT, nullptr, nullptr, nullptr, nullptr);
    // M (bf16)
    k_mfma<MODE_COST><<<dim3(2,2,NB),256,0,stream>>>(
        ZSP_BF, HTT, (long)NN*HTT, ZT_BF, HTT, (long)NN*HTT, HTT,
        nullptr, M_BF+po, NN, (long)NN*NN,
        ws+OFF_NSP, ws+OFF_NT, nullptr, nullptr, nullptr, nullptr);
  }

  // ---- Part B phase 2: Sinkhorn (both passes, multiplicative, K in LDS) ----
  k_sinkhorn_fused<<<2*NB,1024,SINK_DYN_LDS,stream>>>(
      M_BF, ws+OFF_MU, ws+OFF_NU, GN_BF, acc);

  // ---- Part B phase 3: T = Gn@Ct, struct loss (batched over both passes) ----
  k_mfma<MODE_PLAIN><<<dim3(2,2,2*NB),256,0,stream>>>(
      GN_BF, NN, (long)NN*NN, CT_BF, NN, (long)NN*NN, NN,
      nullptr, T_BF, NN, (long)NN*NN,
      nullptr, nullptr, nullptr, nullptr, nullptr, nullptr);
  k_mfma<MODE_STRUCT><<<dim3(2,2,2*NB),256,0,stream>>>(
      T_BF, NN, (long)NN*NN, GN_BF, NN, (long)NN*NN, NN,
      nullptr, nullptr, NN, (long)NN*NN,
      nullptr, nullptr, nullptr, ws+OFF_CS, ws+OFF_MU, acc);

  k_final<<<1,1,0,stream>>>(acc, (float*)d_out);
}

// Round 2
// 735.599 us; speedup vs baseline: 1.1701x; 1.0642x over previous
//
#include <hip/hip_runtime.h>
#include <math.h>

// Problem dims
#define NB   64      // batch B
#define NN   256     // tokens N
#define HSS  768     // H_S
#define HTT  1024    // H_T
#define ROWS (NB*NN) // 16384
#define C2LOG 14.426950408889634f  // 10 * log2(e)

typedef unsigned short u16;
typedef __attribute__((ext_vector_type(8))) short bf16x8;
typedef __attribute__((ext_vector_type(4))) float f32x4;

// swizzled LDS index for K[r][c] (256 cols): chunk rotation, 8-u16 granularity
#define LIDX(r,c) (((r)<<8) + (((((c)>>3) + (r)) & 31)<<3) + ((c)&7))
// swizzled LDS index for E[r][c] (128 cols, 16 chunks of 8)
#define EIDX(r,c) (((r)<<7) + (((((c)>>3) + (r)) & 15)<<3) + ((c)&7))

// async global->LDS, 16B per lane (gfx950)
__device__ __forceinline__ void gl16(const u16* g, u16* l){
  __builtin_amdgcn_global_load_lds(
      (const __attribute__((address_space(1))) unsigned int*)g,
      (__attribute__((address_space(3))) unsigned int*)l,
      16, 0, 0);
}

// ---------------- workspace layout (float offsets) ----------------
static const size_t OFF_ACC   = 0;                          // 16 floats
static const size_t OFF_SQ128 = 16;
static const size_t OFF_SP128 = OFF_SQ128 + 64*128;
static const size_t OFF_TQ128 = OFF_SP128 + 64*128;
static const size_t OFF_TP128 = OFF_TQ128 + 64*128;
static const size_t OFF_SQ768 = OFF_TP128 + 64*128;
static const size_t OFF_SP768 = OFF_SQ768 + 64*768;
static const size_t OFF_DS    = OFF_SP768 + 64*768;         // 128*128
static const size_t OFF_DT    = OFF_DS + 128*128;
static const size_t OFF_CS    = OFF_DT + 128*128;           // 2*B*N*N f32
static const size_t OFF_MBF   = OFF_CS  + (size_t)2*NB*NN*NN;     // 2*B*N*N bf16
static const size_t OFF_ZS_BF = OFF_MBF + (size_t)NB*NN*NN;       // 16384x768 bf16
static const size_t OFF_ZT_BF = OFF_ZS_BF + (size_t)ROWS*HSS/2;   // 16384x1024 bf16
static const size_t OFF_WT_BF = OFF_ZT_BF + (size_t)ROWS*HTT/2;   // 1024x768 bf16
static const size_t OFF_ZSP_BF= OFF_WT_BF + (size_t)HTT*HSS/2;    // 16384x1024 bf16
static const size_t OFF_GN_BF = OFF_ZSP_BF+ (size_t)ROWS*HTT/2;   // 2*B*N*N bf16
static const size_t OFF_CT_BF = OFF_GN_BF + (size_t)NB*NN*NN;     // 2*B*N*N bf16
static const size_t OFF_T_BF  = OFF_ZS_BF;                  // ALIAS: ZS dead after cost GEMMs
static const size_t OFF_NS    = OFF_CT_BF + (size_t)NB*NN*NN;
static const size_t OFF_NT    = OFF_NS + ROWS;
static const size_t OFF_NSP   = OFF_NT + ROWS;
static const size_t OFF_MU    = OFF_NSP + ROWS;             // 2*ROWS (linear)
static const size_t OFF_NU    = OFF_MU + 2*ROWS;            // 2*ROWS (linear)

// acc: 0=contrastive 1=ds_sum 2=dt_sum 3=dist_huber 4=angle_huber 5=feat 6=struct

// ---------------- helpers ----------------
__device__ __forceinline__ float wred_sum(float v){
  #pragma unroll
  for(int o=32;o>0;o>>=1) v += __shfl_xor(v,o,64);
  return v;
}
__device__ __forceinline__ float wred_max(float v){
  #pragma unroll
  for(int o=32;o>0;o>>=1) v = fmaxf(v, __shfl_xor(v,o,64));
  return v;
}
__device__ __forceinline__ u16 f2bf(float f){
  unsigned u = __float_as_uint(f);
  unsigned r = (u + 0x7fffu + ((u>>16)&1u)) >> 16;
  return (u16)r;
}
__device__ __forceinline__ float bf2f(u16 h){
  return __uint_as_float(((unsigned)h)<<16);
}

// ---------------- Part A kernels ----------------
__global__ __launch_bounds__(256) void k_l2norm_rows(const float* __restrict__ in,
    float* __restrict__ out, int k_in, int k_use){
  int r = blockIdx.x;
  const float* row = in + (size_t)r*k_in;
  float ss = 0.f;
  for(int d=threadIdx.x; d<k_use; d+=256){ float x=row[d]; ss += x*x; }
  ss = wred_sum(ss);
  __shared__ float sm[4];
  if((threadIdx.x&63)==0) sm[threadIdx.x>>6]=ss;
  __syncthreads();
  float tot = sm[0]+sm[1]+sm[2]+sm[3];
  float inv = 1.f / fmaxf(sqrtf(tot), 1e-12f);
  for(int d=threadIdx.x; d<k_use; d+=256) out[(size_t)r*k_use + d] = row[d]*inv;
}

// contrastive: one block per row i; 8 waves split the dot-product dim;
// wave 0 does the 64-wide softmax. float4 loads; data is L2-resident.
__global__ __launch_bounds__(512) void k_contrastive(const float* __restrict__ q,
    const float* __restrict__ p, int dim, float weight, float* __restrict__ acc){
  int i = blockIdx.x;
  int j = threadIdx.x & 63;
  int part = threadIdx.x >> 6;           // 0..7
  const float* qi = q + (size_t)i*dim;
  const float* pj = p + (size_t)j*dim;
  int seg = dim >> 3;                    // 96 (dim=768) or 16 (dim=128)
  int d0 = part*seg;
  float dot = 0.f;
  for(int d=d0; d<d0+seg; d+=4){
    float4 a = *(const float4*)(qi+d);
    float4 b = *(const float4*)(pj+d);
    dot = fmaf(a.x,b.x,dot);
    dot = fmaf(a.y,b.y,dot);
    dot = fmaf(a.z,b.z,dot);
    dot = fmaf(a.w,b.w,dot);
  }
  __shared__ float sm[8][64];
  sm[part][j] = dot;
  __syncthreads();
  if(part==0){
    float s = 0.f;
    #pragma unroll
    for(int k=0;k<8;k++) s += sm[k][j];
    s = s / 0.07f;
    float mx = wred_max(s);
    float e = expf(s - mx);
    float Z = wred_sum(e);
    float logZ = mx + logf(Z);
    float diag = __shfl(s, i, 64);
    if(j==0) atomicAdd(acc+0, weight*(logZ - diag)*(1.f/64.f));
  }
}

__global__ __launch_bounds__(128) void k_gram_ds(const float* __restrict__ sb,
    const float* __restrict__ tb, float* __restrict__ ds, float* __restrict__ dt,
    float* __restrict__ acc){
  int r = blockIdx.x, c = threadIdx.x;
  const float* sr = sb + r*128; const float* sc = sb + c*128;
  const float* tr = tb + r*128; const float* tc = tb + c*128;
  float dot_s=0,ssr=0,ssc=0,dot_t=0,tsr=0,tsc=0;
  for(int d=0; d<128; d++){
    float a=sr[d], b=sc[d]; dot_s += a*b; ssr += a*a; ssc += b*b;
    float at=tr[d], bt=tc[d]; dot_t += at*bt; tsr += at*at; tsc += bt*bt;
  }
  float dv = ssr + ssc - 2.f*dot_s;
  float tv = tsr + tsc - 2.f*dot_t;
  ds[r*128+c] = dv; dt[r*128+c] = tv;
  float ms = (c>r)? dv : 0.f;
  float mt = (c>r)? tv : 0.f;
  ms = wred_sum(ms); mt = wred_sum(mt);
  __shared__ float sm[2][2];
  if((threadIdx.x&63)==0){ sm[0][threadIdx.x>>6]=ms; sm[1][threadIdx.x>>6]=mt; }
  __syncthreads();
  if(threadIdx.x==0){ atomicAdd(acc+1, sm[0][0]+sm[0][1]); atomicAdd(acc+2, sm[1][0]+sm[1][1]); }
}

__global__ __launch_bounds__(128) void k_rkd_dist(const float* __restrict__ ds,
    const float* __restrict__ dt, float* __restrict__ acc){
  int r=blockIdx.x, c=threadIdx.x;
  float mean_s = acc[1]*(1.f/8128.f) + 1e-8f;
  float mean_t = acc[2]*(1.f/8128.f) + 1e-8f;
  float h=0.f;
  if(c>r){
    float diff = ds[r*128+c]/mean_s - dt[r*128+c]/mean_t;
    float a = fabsf(diff);
    h = (a<1.f)? 0.5f*a*a : a-0.5f;
  }
  h = wred_sum(h);
  __shared__ float sm[2];
  if((threadIdx.x&63)==0) sm[threadIdx.x>>6]=h;
  __syncthreads();
  if(threadIdx.x==0) atomicAdd(acc+3, sm[0]+sm[1]);
}

// ---- RKD angle via MFMA: psi = E E^T, E in bf16 LDS, huber fused ----
// grid (j, colhalf) = 256 blocks x 256 thr. 64KB dynamic LDS: Es,Et (128x128 bf16).
#define RKD_LDS 65536
__global__ __launch_bounds__(256, 1) void k_rkd_angle_mfma(
    const float* __restrict__ sb, const float* __restrict__ tb,
    float* __restrict__ accp)
{
  extern __shared__ u16 eSh[];
  u16* Es = eSh;
  u16* Et = eSh + 128*128;
  const int j    = blockIdx.x >> 1;
  const int half = blockIdx.x & 1;
  const int tid = threadIdx.x;
  // stage e-vectors: 2 threads per row (i = tid/2, h = tid&1 -> 64 elems)
  {
    const int i = tid >> 1, h = tid & 1;
    #pragma unroll
    for(int which=0; which<2; which++){
      const float* xb = which ? tb : sb;
      u16* E = which ? Et : Es;
      const float* xj = xb + j*128 + h*64;
      const float* xi = xb + i*128 + h*64;
      float ss = 0.f;
      #pragma unroll
      for(int d4=0; d4<16; d4++){
        float4 a = *(const float4*)(xj + d4*4);
        float4 b = *(const float4*)(xi + d4*4);
        float d0=a.x-b.x, d1=a.y-b.y, d2=a.z-b.z, d3=a.w-b.w;
        ss += d0*d0+d1*d1+d2*d2+d3*d3;
      }
      ss += __shfl_xor(ss, 1, 64);
      float inv = (i==j) ? 0.f : 1.f/(sqrtf(ss)+1e-8f);
      #pragma unroll
      for(int d4=0; d4<16; d4++){
        float4 a = *(const float4*)(xj + d4*4);
        float4 b = *(const float4*)(xi + d4*4);
        int c = h*64 + d4*4;
        E[EIDX(i,c+0)] = f2bf((a.x-b.x)*inv);
        E[EIDX(i,c+1)] = f2bf((a.y-b.y)*inv);
        E[EIDX(i,c+2)] = f2bf((a.z-b.z)*inv);
        E[EIDX(i,c+3)] = f2bf((a.w-b.w)*inv);
      }
    }
  }
  __syncthreads();
  // MFMA: wave w computes rows [w*32,w*32+32) x cols [half*64, half*64+64)
  const int w = tid >> 6, lane = tid & 63;
  const int q = lane >> 4, loc = lane & 15;
  float hsum = 0.f;
  #pragma unroll
  for(int ni=0; ni<4; ni++){
    const int cb = half*64 + ni*16;
    #pragma unroll
    for(int mi=0; mi<2; mi++){
      const int rb = w*32 + mi*16;
      f32x4 as_ = {0.f,0.f,0.f,0.f}, at_ = {0.f,0.f,0.f,0.f};
      #pragma unroll
      for(int k0=0; k0<128; k0+=32){
        int ra = rb + loc, rbn = cb + loc;
        int ca = k0 + q*8;
        bf16x8 aS = *(const bf16x8*)(Es + EIDX(ra, ca));
        bf16x8 bS = *(const bf16x8*)(Es + EIDX(rbn, ca));
        bf16x8 aT = *(const bf16x8*)(Et + EIDX(ra, ca));
        bf16x8 bT = *(const bf16x8*)(Et + EIDX(rbn, ca));
        as_ = __builtin_amdgcn_mfma_f32_16x16x32_bf16(aS, bS, as_, 0,0,0);
        at_ = __builtin_amdgcn_mfma_f32_16x16x32_bf16(aT, bT, at_, 0,0,0);
      }
      // huber on diff; D[row][col]: row = rb + q*4 + jj, col = cb + loc
      #pragma unroll
      for(int jj=0; jj<4; jj++){
        int row = rb + q*4 + jj, col = cb + loc;
        if(row != col){
          float d = as_[jj] - at_[jj];
          float a = fabsf(d);
          hsum += (a < 1.f) ? 0.5f*a*a : a - 0.5f;
        }
      }
    }
  }
  hsum = wred_sum(hsum);
  __syncthreads();               // eSh reads done; reuse as scratch
  float* red = (float*)eSh;
  if(lane==0) red[w] = hsum;
  __syncthreads();
  if(tid==0) atomicAdd(accp+4, red[0]+red[1]+red[2]+red[3]);
}

// ---------------- Part B: convert+norm / saliency ----------------
__global__ __launch_bounds__(256) void k_cvt_norm(const float* __restrict__ in,
    u16* __restrict__ out, float* __restrict__ nrm, int K){
  int r = blockIdx.x;
  const float* row = in + (size_t)r*K;
  u16* orow = out + (size_t)r*K;
  float ss=0.f;
  for(int d=threadIdx.x; d<K; d+=256){ float x=row[d]; ss+=x*x; orow[d]=f2bf(x); }
  ss = wred_sum(ss);
  __shared__ float sm[4];
  if((threadIdx.x&63)==0) sm[threadIdx.x>>6]=ss;
  __syncthreads();
  if(threadIdx.x==0) nrm[r] = sqrtf(sm[0]+sm[1]+sm[2]+sm[3]);
}

__global__ __launch_bounds__(256) void k_row_norm_bf16(const u16* __restrict__ z,
    float* __restrict__ nrm, int K){
  int r = blockIdx.x;
  const u16* row = z + (size_t)r*K;
  float ss=0.f;
  for(int d=threadIdx.x; d<K; d+=256){ float x=bf2f(row[d]); ss+=x*x; }
  ss = wred_sum(ss);
  __shared__ float sm[4];
  if((threadIdx.x&63)==0) sm[threadIdx.x>>6]=ss;
  __syncthreads();
  if(threadIdx.x==0) nrm[r] = sqrtf(sm[0]+sm[1]+sm[2]+sm[3]);
}

// W (HSS x HTT) f32 -> Wt (HTT x HSS) bf16
__global__ void k_wt(const float* __restrict__ W, u16* __restrict__ Wt){
  __shared__ float t[32][33];
  int k0 = blockIdx.y*32, n0 = blockIdx.x*32;
  int tx = threadIdx.x, ty = threadIdx.y;
  for(int r=0;r<32;r+=8) t[ty+r][tx] = W[(size_t)(k0+ty+r)*HTT + n0+tx];
  __syncthreads();
  for(int r=0;r<32;r+=8) Wt[(size_t)(n0+ty+r)*HSS + k0+tx] = f2bf(t[tx][ty+r]);
}

// softmax over N (linear output)
__global__ __launch_bounds__(256) void k_saliency(const float* __restrict__ nrm,
    float* __restrict__ out){
  int b = blockIdx.x, n = threadIdx.x;
  float x = nrm[b*NN+n];
  float mx = wred_max(x);
  __shared__ float sm[4], sm2[4];
  if((n&63)==0) sm[n>>6]=mx;
  __syncthreads();
  mx = fmaxf(fmaxf(sm[0],sm[1]),fmaxf(sm[2],sm[3]));
  float e = expf(x-mx);
  float s = wred_sum(e);
  if((n&63)==0) sm2[n>>6]=s;
  __syncthreads();
  s = sm2[0]+sm2[1]+sm2[2]+sm2[3];
  out[b*NN+n] = e/s;
}

// ---------------- MFMA GEMM (NT form) ----------------
enum { MODE_PROJ=0, MODE_COST=1, MODE_PLAIN=2, MODE_STRUCT=3 };

template<int MODE>
__global__ __launch_bounds__(256) void k_mfma(
    const u16* __restrict__ A, int lda, long bA,
    const u16* __restrict__ B, int ldb, long bB,
    int K,
    float* __restrict__ outF, u16* __restrict__ outB, int ldo, long bO,
    const float* __restrict__ nx, const float* __restrict__ ny,
    const float* __restrict__ bias,
    const float* __restrict__ Cs, const float* __restrict__ mu,
    float* __restrict__ accp)
{
  __shared__ u16 As[128*32];
  __shared__ u16 Bs[128*32];
  __shared__ float red[4];

  // XCD-aware bijective block swizzle: all grids here have nwg % 8 == 0.
  // Groups blocks sharing A/B panels onto the same XCD L2.
  int gx = gridDim.x, gy = gridDim.y;
  int flat = blockIdx.x + gx*(blockIdx.y + gy*blockIdx.z);
  int nwg  = gx*gy*gridDim.z;
  int cpx  = nwg >> 3;
  int lg   = (flat & 7)*cpx + (flat >> 3);
  int bx   = lg % gx;
  int rest = lg / gx;
  int by   = rest % gy;
  int b    = rest / gy;

  const u16* Ab = A + (size_t)b*bA;
  const u16* Bb = B + (size_t)b*bB;
  int tid = threadIdx.x;
  int lane = tid & 63, w = tid >> 6;
  int m0 = by*128, n0 = bx*128;
  int row_off = (w>>1)*64, col_off = (w&1)*64;
  int q = lane>>4, loc = lane&15;
  f32x4 acc[4][4] = {};

  // staging geometry: linear LDS dest (global_load_lds requirement),
  // chunk swizzle applied on the GLOBAL source address (rule: both-sides).
  // wave w, half h covers LDS bytes [h*4096 + w*1024, +1024): row = h*64+w*16+(lane>>2), slot = lane&3.
  const int srow = (lane >> 2);
  const int sslot = lane & 3;

  for(int k0=0;k0<K;k0+=32){
    #pragma unroll
    for(int h=0;h<2;h++){
      int row = h*64 + w*16 + srow;
      int ca  = (sslot ^ ((row>>1)&3))*8;            // inverse of read-side XOR
      u16* ldst = As + h*2048 + w*512 + lane*8;      // linear: row*32 + slot*8
      u16* ldstB= Bs + h*2048 + w*512 + lane*8;
      gl16(Ab + (size_t)(m0+row)*lda + k0 + ca, ldst);
      gl16(Bb + (size_t)(n0+row)*ldb + k0 + ca, ldstB);
    }
    __syncthreads();
    bf16x8 af[4], bfr[4];
    #pragma unroll
    for(int mi=0;mi<4;mi++){
      int r = row_off + mi*16 + loc;
      int slot = q ^ ((r>>1)&3);
      af[mi] = *(const bf16x8*)(As + r*32 + slot*8);
    }
    #pragma unroll
    for(int ni=0;ni<4;ni++){
      int r = col_off + ni*16 + loc;
      int slot = q ^ ((r>>1)&3);
      bfr[ni] = *(const bf16x8*)(Bs + r*32 + slot*8);
    }
    #pragma unroll
    for(int mi=0;mi<4;mi++)
      #pragma unroll
      for(int ni=0;ni<4;ni++)
        acc[mi][ni] = __builtin_amdgcn_mfma_f32_16x16x32_bf16(af[mi], bfr[ni], acc[mi][ni], 0,0,0);
    __syncthreads();
  }

  float* outFb = outF ? outF + (size_t)b*bO : nullptr;
  u16*   outBb = outB ? outB + (size_t)b*bO : nullptr;
  const float* nxb = nx ? nx + (size_t)b*NN : nullptr;
  const float* nyb = ny ? ny + (size_t)b*NN : nullptr;
  const float* Cb  = (MODE==MODE_STRUCT) ? Cs + (size_t)b*bO : nullptr;
  const float* mb  = (MODE==MODE_STRUCT) ? mu + (size_t)b*NN : nullptr;
  float lsum = 0.f;
  #pragma unroll
  for(int mi=0;mi<4;mi++){
    #pragma unroll
    for(int j=0;j<4;j++){
      int row = m0 + row_off + mi*16 + q*4 + j;
      float ir = 0.f, mr = 0.f;
      if(MODE==MODE_COST)   ir = 1.f/fmaxf(nxb[row],1e-12f);
      if(MODE==MODE_STRUCT) mr = mb[row];
      #pragma unroll
      for(int ni=0;ni<4;ni++){
        int col = n0 + col_off + ni*16 + loc;
        float v = acc[mi][ni][j];
        if(MODE==MODE_PROJ){
          v += bias[col];
          outBb[(size_t)row*ldo + col] = f2bf(v);
        } else if(MODE==MODE_COST){
          float ic = 1.f/fmaxf(nyb[col],1e-12f);
          v = 1.f - v*ir*ic;
          if(outFb) outFb[(size_t)row*ldo + col] = v;
          if(outBb) outBb[(size_t)row*ldo + col] = f2bf(v);
        } else if(MODE==MODE_PLAIN){
          outBb[(size_t)row*ldo + col] = f2bf(v);
        } else {
          float d = Cb[(size_t)row*ldo + col] - v;
          lsum += d*d*mr*mb[col];
        }
      }
    }
  }
  if(MODE==MODE_STRUCT){
    lsum = wred_sum(lsum);
    if(lane==0) red[w] = lsum;
    __syncthreads();
    if(tid==0) atomicAdd(accp+6, red[0]+red[1]+red[2]+red[3]);
  }
}

// ---------------- fused Sinkhorn: multiplicative domain, K in LDS ----------------
#define SINK_DYN_LDS 131072
__global__ __launch_bounds__(1024, 1) void k_sinkhorn_fused(
    const u16* __restrict__ Mbf, const float* __restrict__ muL,
    const float* __restrict__ nuL, u16* __restrict__ Gn, float* __restrict__ accp)
{
  extern __shared__ u16 Ks[];                      // 256x256 bf16, swizzled
  __shared__ __align__(16) float part[4096];       // reduction scratch
  __shared__ __align__(16) float su[NN], sv[NN], smu[NN], snu[NN];
  __shared__ float red[16];

  const int b = blockIdx.x;
  const int t = threadIdx.x;
  const u16* Mb = Mbf + (size_t)b*NN*NN;

  #pragma unroll
  for(int i=0;i<16;i++){
    int e = (i*1024 + t)*4;
    int r = e>>8, c = e&255;
    ushort4 mv = *(const ushort4*)(Mb + e);
    ushort4 o;
    o.x = f2bf(exp2f(-C2LOG*bf2f(mv.x)));
    o.y = f2bf(exp2f(-C2LOG*bf2f(mv.y)));
    o.z = f2bf(exp2f(-C2LOG*bf2f(mv.z)));
    o.w = f2bf(exp2f(-C2LOG*bf2f(mv.w)));
    *(ushort4*)(Ks + LIDX(r,c)) = o;
  }
  if(t < NN){
    smu[t] = muL[(size_t)b*NN+t] + 1e-8f;
    snu[t] = nuL[(size_t)b*NN+t] + 1e-8f;
    sv[t] = 1.f;
  }
  __syncthreads();

  const int r_ = t & 255, p_ = t >> 8;
  const int w = t>>6, l = t&63;

  for(int it=0; it<20; it++){
    {
      float sacc = 0.f;
      #pragma unroll
      for(int jj=0;jj<8;jj++){
        int c0 = p_*64 + jj*8;
        uint4 kv = *(const uint4*)(Ks + LIDX(r_, c0));
        float4 va = *(const float4*)(sv + c0);
        float4 vb = *(const float4*)(sv + c0 + 4);
        sacc += __uint_as_float(kv.x<<16)          * va.x;
        sacc += __uint_as_float(kv.x & 0xffff0000u)* va.y;
        sacc += __uint_as_float(kv.y<<16)          * va.z;
        sacc += __uint_as_float(kv.y & 0xffff0000u)* va.w;
        sacc += __uint_as_float(kv.z<<16)          * vb.x;
        sacc += __uint_as_float(kv.z & 0xffff0000u)* vb.y;
        sacc += __uint_as_float(kv.w<<16)          * vb.z;
        sacc += __uint_as_float(kv.w & 0xffff0000u)* vb.w;
      }
      part[t] = sacc;
    }
    __syncthreads();
    if(t < NN){
      float S = part[t] + part[256+t] + part[512+t] + part[768+t];
      su[t] = smu[t] / S;
    }
    __syncthreads();
    {
      float cs0=0.f,cs1=0.f,cs2=0.f,cs3=0.f;
      #pragma unroll
      for(int rr=0;rr<16;rr++){
        int r = w*16 + rr;
        ushort4 kv = *(const ushort4*)(Ks + LIDX(r, l*4));
        float ur = su[r];
        cs0 = fmaf(bf2f(kv.x), ur, cs0);
        cs1 = fmaf(bf2f(kv.y), ur, cs1);
        cs2 = fmaf(bf2f(kv.z), ur, cs2);
        cs3 = fmaf(bf2f(kv.w), ur, cs3);
      }
      float4 o; o.x=cs0; o.y=cs1; o.z=cs2; o.w=cs3;
      *(float4*)(part + w*256 + l*4) = o;
    }
    __syncthreads();
    if(t < NN){
      float S = 0.f;
      #pragma unroll
      for(int ww=0;ww<16;ww++) S += part[ww*256 + t];
      sv[t] = snu[t] / S;
    }
    __syncthreads();
  }

  {
    float sacc = 0.f;
    #pragma unroll
    for(int jj=0;jj<8;jj++){
      int c0 = p_*64 + jj*8;
      uint4 kv = *(const uint4*)(Ks + LIDX(r_, c0));
      float4 va = *(const float4*)(sv + c0);
      float4 vb = *(const float4*)(sv + c0 + 4);
      sacc += __uint_as_float(kv.x<<16)          * va.x;
      sacc += __uint_as_float(kv.x & 0xffff0000u)* va.y;
      sacc += __uint_as_float(kv.y<<16)          * va.z;
      sacc += __uint_as_float(kv.y & 0xffff0000u)* va.w;
      sacc += __uint_as_float(kv.z<<16)          * vb.x;
      sacc += __uint_as_float(kv.z & 0xffff0000u)* vb.y;
      sacc += __uint_as_float(kv.w<<16)          * vb.z;
      sacc += __uint_as_float(kv.w & 0xffff0000u)* vb.w;
    }
    part[t] = sacc;
  }
  __syncthreads();
  if(t < NN){
    float S = part[t] + part[256+t] + part[512+t] + part[768+t];
    smu[t] = 1.f / (su[t]*S + 1e-8f);
  }
  __syncthreads();

  u16* Gb = Gn + (size_t)b*NN*NN;
  const float IC = -1.f/C2LOG;
  float v0 = sv[l*4+0], v1 = sv[l*4+1], v2 = sv[l*4+2], v3 = sv[l*4+3];
  float fl = 0.f;
  for(int rr=0;rr<16;rr++){
    int r = w*16 + rr;
    ushort4 kv = *(const ushort4*)(Ks + LIDX(r, l*4));
    float k0=bf2f(kv.x), k1=bf2f(kv.y), k2=bf2f(kv.z), k3=bf2f(kv.w);
    float ur = su[r], inv = smu[r];
    float g0=ur*k0*v0, g1=ur*k1*v1, g2=ur*k2*v2, g3=ur*k3*v3;
    fl += g0*(__log2f(k0)*IC) + g1*(__log2f(k1)*IC)
        + g2*(__log2f(k2)*IC) + g3*(__log2f(k3)*IC);
    ushort4 o;
    o.x=f2bf(g0*inv); o.y=f2bf(g1*inv); o.z=f2bf(g2*inv); o.w=f2bf(g3*inv);
    *(ushort4*)(Gb + (size_t)r*NN + l*4) = o;
  }
  fl = wred_sum(fl);
  if(l==0) red[w] = fl;
  __syncthreads();
  if(t==0){
    float s=0.f;
    #pragma unroll
    for(int i=0;i<16;i++) s+=red[i];
    atomicAdd(accp+5, s);
  }
}

__global__ void k_final(const float* __restrict__ acc, float* __restrict__ out){
  out[0] = acc[0]
         + 20.f*acc[3]*(1.f/8128.f)
         + 40.f*acc[4]*(1.f/2048256.f)
         + 0.25f*(acc[5]+acc[6])*(1.f/64.f);
}

// ---------------- host ----------------
extern "C" void kernel_launch(void* const* d_in, const int* in_sizes, int n_in,
                              void* d_out, int out_size, void* d_ws, size_t ws_size,
                              hipStream_t stream) {
  const float* s_q_reps   = (const float*)d_in[0];
  const float* s_p_reps   = (const float*)d_in[1];
  const float* t_q_reps   = (const float*)d_in[2];
  const float* t_p_reps   = (const float*)d_in[3];
  const float* s_q_states = (const float*)d_in[4];
  const float* s_p_states = (const float*)d_in[5];
  const float* t_q_states = (const float*)d_in[6];
  const float* t_p_states = (const float*)d_in[7];
  const float* proj_w     = (const float*)d_in[8];
  const float* proj_b     = (const float*)d_in[9];
  float* ws = (float*)d_ws;
  float* acc = ws + OFF_ACC;
  u16* M_BF   = (u16*)(ws + OFF_MBF);
  u16* ZS_BF  = (u16*)(ws + OFF_ZS_BF);
  u16* ZT_BF  = (u16*)(ws + OFF_ZT_BF);
  u16* WT_BF  = (u16*)(ws + OFF_WT_BF);
  u16* ZSP_BF = (u16*)(ws + OFF_ZSP_BF);
  u16* GN_BF  = (u16*)(ws + OFF_GN_BF);
  u16* CT_BF  = (u16*)(ws + OFF_CT_BF);
  u16* T_BF   = (u16*)(ws + OFF_T_BF);

  hipFuncSetAttribute(reinterpret_cast<const void*>(k_sinkhorn_fused),
                      hipFuncAttributeMaxDynamicSharedMemorySize, SINK_DYN_LDS);
  hipFuncSetAttribute(reinterpret_cast<const void*>(k_rkd_angle_mfma),
                      hipFuncAttributeMaxDynamicSharedMemorySize, RKD_LDS);

  hipMemsetAsync(acc, 0, 16*sizeof(float), stream);

  // ---- Part A ----
  k_l2norm_rows<<<64,256,0,stream>>>(s_q_reps, ws+OFF_SQ128, 768, 128);
  k_l2norm_rows<<<64,256,0,stream>>>(s_p_reps, ws+OFF_SP128, 768, 128);
  k_l2norm_rows<<<64,256,0,stream>>>(t_q_reps, ws+OFF_TQ128, 768, 128);
  k_l2norm_rows<<<64,256,0,stream>>>(t_p_reps, ws+OFF_TP128, 768, 128);
  k_l2norm_rows<<<64,256,0,stream>>>(s_q_reps, ws+OFF_SQ768, 768, 768);
  k_l2norm_rows<<<64,256,0,stream>>>(s_p_reps, ws+OFF_SP768, 768, 768);
  k_contrastive<<<64,512,0,stream>>>(ws+OFF_SQ128, ws+OFF_SP128, 128, 1.0f, acc);
  k_contrastive<<<64,512,0,stream>>>(ws+OFF_SQ768, ws+OFF_SP768, 768, 2.0f, acc);
  k_gram_ds<<<128,128,0,stream>>>(ws+OFF_SQ128, ws+OFF_TQ128, ws+OFF_DS, ws+OFF_DT, acc);
  k_rkd_dist<<<128,128,0,stream>>>(ws+OFF_DS, ws+OFF_DT, acc);
  k_rkd_angle_mfma<<<256,256,RKD_LDS,stream>>>(ws+OFF_SQ128, ws+OFF_TQ128, acc);

  k_wt<<<dim3(HTT/32, HSS/32),dim3(32,8),0,stream>>>(proj_w, WT_BF);

  // ---- Part B phase 1: per-pass GEMMs into doubled buffers ----
  for(int pass=0; pass<2; pass++){
    const float* zs = pass ? s_p_states : s_q_states;
    const float* zt = pass ? t_p_states : t_q_states;
    size_t po  = (size_t)pass*NB*NN*NN;
    size_t pr  = (size_t)pass*ROWS;
    k_cvt_norm<<<ROWS,256,0,stream>>>(zs, ZS_BF, ws+OFF_NS, HSS);
    k_cvt_norm<<<ROWS,256,0,stream>>>(zt, ZT_BF, ws+OFF_NT, HTT);
    k_saliency<<<NB,256,0,stream>>>(ws+OFF_NS, ws+OFF_MU+pr);
    k_saliency<<<NB,256,0,stream>>>(ws+OFF_NT, ws+OFF_NU+pr);
    k_mfma<MODE_PROJ><<<dim3(HTT/128, ROWS/128, 1),256,0,stream>>>(
        ZS_BF, HSS, 0, WT_BF, HSS, 0, HSS,
        nullptr, ZSP_BF, HTT, 0,
        nullptr, nullptr, proj_b, nullptr, nullptr, nullptr);
    k_row_norm_bf16<<<ROWS,256,0,stream>>>(ZSP_BF, ws+OFF_NSP, HTT);
    // C_s (f32)
    k_mfma<MODE_COST><<<dim3(2,2,NB),256,0,stream>>>(
        ZS_BF, HSS, (long)NN*HSS, ZS_BF, HSS, (long)NN*HSS, HSS,
        ws+OFF_CS+po, nullptr, NN, (long)NN*NN,
        ws+OFF_NS, ws+OFF_NS, nullptr, nullptr, nullptr, nullptr);
    // C_t (bf16)
    k_mfma<MODE_COST><<<dim3(2,2,NB),256,0,stream>>>(
        ZT_BF, HTT, (long)NN*HTT, ZT_BF, HTT, (long)NN*HTT, HTT,
        nullptr, CT_BF+po, NN, (long)NN*NN,
        ws+OFF_NT, ws+OFF_NT, nullptr, nullptr, nullptr, nullptr);
    // M (bf16)
    k_mfma<MODE_COST><<<dim3(2,2,NB),256,0,stream>>>(
        ZSP_BF, HTT, (long)NN*HTT, ZT_BF, HTT, (long)NN*HTT, HTT,
        nullptr, M_BF+po, NN, (long)NN*NN,
        ws+OFF_NSP, ws+OFF_NT, nullptr, nullptr, nullptr, nullptr);
  }

  // ---- Part B phase 2: Sinkhorn (both passes, multiplicative, K in LDS) ----
  k_sinkhorn_fused<<<2*NB,1024,SINK_DYN_LDS,stream>>>(
      M_BF, ws+OFF_MU, ws+OFF_NU, GN_BF, acc);

  // ---- Part B phase 3: T = Gn@Ct, struct loss (batched over both passes) ----
  k_mfma<MODE_PLAIN><<<dim3(2,2,2*NB),256,0,stream>>>(
      GN_BF, NN, (long)NN*NN, CT_BF, NN, (long)NN*NN, NN,
      nullptr, T_BF, NN, (long)NN*NN,
      nullptr, nullptr, nullptr, nullptr, nullptr, nullptr);
  k_mfma<MODE_STRUCT><<<dim3(2,2,2*NB),256,0,stream>>>(
      T_BF, NN, (long)NN*NN, GN_BF, NN, (long)NN*NN, NN,
      nullptr, nullptr, NN, (long)NN*NN,
      nullptr, nullptr, nullptr, ws+OFF_CS, ws+OFF_MU, acc);

  k_final<<<1,1,0,stream>>>(acc, (float*)d_out);
}

// Round 3
// 718.420 us; speedup vs baseline: 1.1980x; 1.0239x over previous
//
#include <hip/hip_runtime.h>
#include <math.h>

// Problem dims
#define NB   64      // batch B
#define NN   256     // tokens N
#define HSS  768     // H_S
#define HTT  1024    // H_T
#define ROWS (NB*NN) // 16384
#define C2LOG 14.426950408889634f  // 10 * log2(e)

typedef unsigned short u16;
typedef __attribute__((ext_vector_type(8))) short bf16x8;
typedef __attribute__((ext_vector_type(4))) float f32x4;

// swizzled LDS index for K[r][c] (256 cols): chunk rotation, 8-u16 granularity
#define LIDX(r,c) (((r)<<8) + (((((c)>>3) + (r)) & 31)<<3) + ((c)&7))
// swizzled LDS index for E[r][c] (128 cols, 16 chunks of 8)
#define EIDX(r,c) (((r)<<7) + (((((c)>>3) + (r)) & 15)<<3) + ((c)&7))

// async global->LDS, 16B per lane (gfx950)
__device__ __forceinline__ void gl16(const u16* g, u16* l){
  __builtin_amdgcn_global_load_lds(
      (const __attribute__((address_space(1))) unsigned int*)g,
      (__attribute__((address_space(3))) unsigned int*)l,
      16, 0, 0);
}

// ---------------- workspace layout (float offsets) ----------------
static const size_t OFF_ACC   = 0;                          // 16 floats
static const size_t OFF_SQ128 = 16;
static const size_t OFF_SP128 = OFF_SQ128 + 64*128;
static const size_t OFF_TQ128 = OFF_SP128 + 64*128;
static const size_t OFF_TP128 = OFF_TQ128 + 64*128;
static const size_t OFF_SQ768 = OFF_TP128 + 64*128;
static const size_t OFF_SP768 = OFF_SQ768 + 64*768;
static const size_t OFF_DS    = OFF_SP768 + 64*768;         // 128*128
static const size_t OFF_DT    = OFF_DS + 128*128;
static const size_t OFF_CS    = OFF_DT + 128*128;           // 2*B*N*N f32
static const size_t OFF_MBF   = OFF_CS  + (size_t)2*NB*NN*NN;     // 2*B*N*N bf16
static const size_t OFF_ZS_BF = OFF_MBF + (size_t)NB*NN*NN;       // 16384x768 bf16
static const size_t OFF_ZT_BF = OFF_ZS_BF + (size_t)ROWS*HSS/2;   // 16384x1024 bf16
static const size_t OFF_WT_BF = OFF_ZT_BF + (size_t)ROWS*HTT/2;   // 1024x768 bf16
static const size_t OFF_ZSP_BF= OFF_WT_BF + (size_t)HTT*HSS/2;    // 16384x1024 bf16
static const size_t OFF_GN_BF = OFF_ZSP_BF+ (size_t)ROWS*HTT/2;   // 2*B*N*N bf16
static const size_t OFF_CT_BF = OFF_GN_BF + (size_t)NB*NN*NN;     // 2*B*N*N bf16
static const size_t OFF_T_BF  = OFF_ZS_BF;                  // ALIAS: ZS dead after cost GEMMs
static const size_t OFF_NS    = OFF_CT_BF + (size_t)NB*NN*NN;
static const size_t OFF_NT    = OFF_NS + ROWS;
static const size_t OFF_NSP   = OFF_NT + ROWS;
static const size_t OFF_MU    = OFF_NSP + ROWS;             // 2*ROWS (linear)
static const size_t OFF_NU    = OFF_MU + 2*ROWS;            // 2*ROWS (linear)

// acc: 0=contrastive 1=ds_sum 2=dt_sum 3=dist_huber 4=angle_huber 5=feat 6=struct

// ---------------- helpers ----------------
__device__ __forceinline__ float wred_sum(float v){
  #pragma unroll
  for(int o=32;o>0;o>>=1) v += __shfl_xor(v,o,64);
  return v;
}
__device__ __forceinline__ float wred_max(float v){
  #pragma unroll
  for(int o=32;o>0;o>>=1) v = fmaxf(v, __shfl_xor(v,o,64));
  return v;
}
__device__ __forceinline__ u16 f2bf(float f){
  unsigned u = __float_as_uint(f);
  unsigned r = (u + 0x7fffu + ((u>>16)&1u)) >> 16;
  return (u16)r;
}
__device__ __forceinline__ float bf2f(u16 h){
  return __uint_as_float(((unsigned)h)<<16);
}
__device__ __forceinline__ float rdlane(float v, int srcLane){
  return __uint_as_float(__builtin_amdgcn_readlane(__float_as_uint(v), srcLane));
}

// ---------------- Part A kernels ----------------
// fused 6-way l2norm: blocks 0..255 -> 128-dim slices of {sq,sp,tq,tp};
// blocks 256..383 -> 768-dim of {sq,sp}
__global__ __launch_bounds__(256) void k_l2norm_all(
    const float* __restrict__ sq, const float* __restrict__ sp,
    const float* __restrict__ tq, const float* __restrict__ tp,
    float* __restrict__ ws){
  int bid = blockIdx.x;
  int r = bid & 63;
  const float* in; float* out; int kuse;
  if(bid < 64)       { in = sq; out = ws + OFF_SQ128; kuse = 128; }
  else if(bid < 128) { in = sp; out = ws + OFF_SP128; kuse = 128; }
  else if(bid < 192) { in = tq; out = ws + OFF_TQ128; kuse = 128; }
  else if(bid < 256) { in = tp; out = ws + OFF_TP128; kuse = 128; }
  else if(bid < 320) { in = sq; out = ws + OFF_SQ768; kuse = 768; }
  else               { in = sp; out = ws + OFF_SP768; kuse = 768; }
  const float* row = in + (size_t)r*768;
  float ss = 0.f;
  for(int d=threadIdx.x; d<kuse; d+=256){ float x=row[d]; ss += x*x; }
  ss = wred_sum(ss);
  __shared__ float sm[4];
  if((threadIdx.x&63)==0) sm[threadIdx.x>>6]=ss;
  __syncthreads();
  float tot = sm[0]+sm[1]+sm[2]+sm[3];
  float inv = 1.f / fmaxf(sqrtf(tot), 1e-12f);
  for(int d=threadIdx.x; d<kuse; d+=256) out[(size_t)r*kuse + d] = row[d]*inv;
}

// fused contrastive (both matryoshka dims): blocks 0..63 dim=128 w=1, 64..127 dim=768 w=2
__global__ __launch_bounds__(512) void k_contrastive2(const float* __restrict__ ws,
    float* __restrict__ acc){
  int bid = blockIdx.x;
  int i = bid & 63;
  int big = bid >> 6;
  const float* q = ws + (big ? OFF_SQ768 : OFF_SQ128);
  const float* p = ws + (big ? OFF_SP768 : OFF_SP128);
  int dim = big ? 768 : 128;
  float weight = big ? 2.f : 1.f;
  int j = threadIdx.x & 63;
  int part = threadIdx.x >> 6;           // 0..7
  const float* qi = q + (size_t)i*dim;
  const float* pj = p + (size_t)j*dim;
  int seg = dim >> 3;
  int d0 = part*seg;
  float dot = 0.f;
  for(int d=d0; d<d0+seg; d+=4){
    float4 a = *(const float4*)(qi+d);
    float4 b = *(const float4*)(pj+d);
    dot = fmaf(a.x,b.x,dot);
    dot = fmaf(a.y,b.y,dot);
    dot = fmaf(a.z,b.z,dot);
    dot = fmaf(a.w,b.w,dot);
  }
  __shared__ float sm[8][64];
  sm[part][j] = dot;
  __syncthreads();
  if(part==0){
    float s = 0.f;
    #pragma unroll
    for(int k=0;k<8;k++) s += sm[k][j];
    s = s / 0.07f;
    float mx = wred_max(s);
    float e = expf(s - mx);
    float Z = wred_sum(e);
    float logZ = mx + logf(Z);
    float diag = __shfl(s, i, 64);
    if(j==0) atomicAdd(acc+0, weight*(logZ - diag)*(1.f/64.f));
  }
}

__global__ __launch_bounds__(128) void k_gram_ds(const float* __restrict__ sb,
    const float* __restrict__ tb, float* __restrict__ ds, float* __restrict__ dt,
    float* __restrict__ acc){
  int r = blockIdx.x, c = threadIdx.x;
  const float* sr = sb + r*128; const float* sc = sb + c*128;
  const float* tr = tb + r*128; const float* tc = tb + c*128;
  float dot_s=0,ssr=0,ssc=0,dot_t=0,tsr=0,tsc=0;
  for(int d=0; d<128; d++){
    float a=sr[d], b=sc[d]; dot_s += a*b; ssr += a*a; ssc += b*b;
    float at=tr[d], bt=tc[d]; dot_t += at*bt; tsr += at*at; tsc += bt*bt;
  }
  float dv = ssr + ssc - 2.f*dot_s;
  float tv = tsr + tsc - 2.f*dot_t;
  ds[r*128+c] = dv; dt[r*128+c] = tv;
  float ms = (c>r)? dv : 0.f;
  float mt = (c>r)? tv : 0.f;
  ms = wred_sum(ms); mt = wred_sum(mt);
  __shared__ float sm[2][2];
  if((threadIdx.x&63)==0){ sm[0][threadIdx.x>>6]=ms; sm[1][threadIdx.x>>6]=mt; }
  __syncthreads();
  if(threadIdx.x==0){ atomicAdd(acc+1, sm[0][0]+sm[0][1]); atomicAdd(acc+2, sm[1][0]+sm[1][1]); }
}

__global__ __launch_bounds__(128) void k_rkd_dist(const float* __restrict__ ds,
    const float* __restrict__ dt, float* __restrict__ acc){
  int r=blockIdx.x, c=threadIdx.x;
  float mean_s = acc[1]*(1.f/8128.f) + 1e-8f;
  float mean_t = acc[2]*(1.f/8128.f) + 1e-8f;
  float h=0.f;
  if(c>r){
    float diff = ds[r*128+c]/mean_s - dt[r*128+c]/mean_t;
    float a = fabsf(diff);
    h = (a<1.f)? 0.5f*a*a : a-0.5f;
  }
  h = wred_sum(h);
  __shared__ float sm[2];
  if((threadIdx.x&63)==0) sm[threadIdx.x>>6]=h;
  __syncthreads();
  if(threadIdx.x==0) atomicAdd(acc+3, sm[0]+sm[1]);
}

// ---- RKD angle via MFMA: psi = E E^T, E in bf16 LDS, huber fused ----
#define RKD_LDS 65536
__global__ __launch_bounds__(256, 1) void k_rkd_angle_mfma(
    const float* __restrict__ sb, const float* __restrict__ tb,
    float* __restrict__ accp)
{
  extern __shared__ u16 eSh[];
  u16* Es = eSh;
  u16* Et = eSh + 128*128;
  const int j    = blockIdx.x >> 1;
  const int half = blockIdx.x & 1;
  const int tid = threadIdx.x;
  {
    const int i = tid >> 1, h = tid & 1;
    #pragma unroll
    for(int which=0; which<2; which++){
      const float* xb = which ? tb : sb;
      u16* E = which ? Et : Es;
      const float* xj = xb + j*128 + h*64;
      const float* xi = xb + i*128 + h*64;
      float ss = 0.f;
      #pragma unroll
      for(int d4=0; d4<16; d4++){
        float4 a = *(const float4*)(xj + d4*4);
        float4 b = *(const float4*)(xi + d4*4);
        float d0=a.x-b.x, d1=a.y-b.y, d2=a.z-b.z, d3=a.w-b.w;
        ss += d0*d0+d1*d1+d2*d2+d3*d3;
      }
      ss += __shfl_xor(ss, 1, 64);
      float inv = (i==j) ? 0.f : 1.f/(sqrtf(ss)+1e-8f);
      #pragma unroll
      for(int d4=0; d4<16; d4++){
        float4 a = *(const float4*)(xj + d4*4);
        float4 b = *(const float4*)(xi + d4*4);
        int c = h*64 + d4*4;
        E[EIDX(i,c+0)] = f2bf((a.x-b.x)*inv);
        E[EIDX(i,c+1)] = f2bf((a.y-b.y)*inv);
        E[EIDX(i,c+2)] = f2bf((a.z-b.z)*inv);
        E[EIDX(i,c+3)] = f2bf((a.w-b.w)*inv);
      }
    }
  }
  __syncthreads();
  const int w = tid >> 6, lane = tid & 63;
  const int q = lane >> 4, loc = lane & 15;
  float hsum = 0.f;
  #pragma unroll
  for(int ni=0; ni<4; ni++){
    const int cb = half*64 + ni*16;
    #pragma unroll
    for(int mi=0; mi<2; mi++){
      const int rb = w*32 + mi*16;
      f32x4 as_ = {0.f,0.f,0.f,0.f}, at_ = {0.f,0.f,0.f,0.f};
      #pragma unroll
      for(int k0=0; k0<128; k0+=32){
        int ra = rb + loc, rbn = cb + loc;
        int ca = k0 + q*8;
        bf16x8 aS = *(const bf16x8*)(Es + EIDX(ra, ca));
        bf16x8 bS = *(const bf16x8*)(Es + EIDX(rbn, ca));
        bf16x8 aT = *(const bf16x8*)(Et + EIDX(ra, ca));
        bf16x8 bT = *(const bf16x8*)(Et + EIDX(rbn, ca));
        as_ = __builtin_amdgcn_mfma_f32_16x16x32_bf16(aS, bS, as_, 0,0,0);
        at_ = __builtin_amdgcn_mfma_f32_16x16x32_bf16(aT, bT, at_, 0,0,0);
      }
      #pragma unroll
      for(int jj=0; jj<4; jj++){
        int row = rb + q*4 + jj, col = cb + loc;
        if(row != col){
          float d = as_[jj] - at_[jj];
          float a = fabsf(d);
          hsum += (a < 1.f) ? 0.5f*a*a : a - 0.5f;
        }
      }
    }
  }
  hsum = wred_sum(hsum);
  __syncthreads();
  float* red = (float*)eSh;
  if(lane==0) red[w] = hsum;
  __syncthreads();
  if(tid==0) atomicAdd(accp+4, red[0]+red[1]+red[2]+red[3]);
}

// ---------------- Part B: convert+norm / saliency ----------------
__global__ __launch_bounds__(256) void k_cvt_norm(const float* __restrict__ in,
    u16* __restrict__ out, float* __restrict__ nrm, int K){
  int r = blockIdx.x;
  const float* row = in + (size_t)r*K;
  u16* orow = out + (size_t)r*K;
  float ss=0.f;
  for(int d=threadIdx.x; d<K; d+=256){ float x=row[d]; ss+=x*x; orow[d]=f2bf(x); }
  ss = wred_sum(ss);
  __shared__ float sm[4];
  if((threadIdx.x&63)==0) sm[threadIdx.x>>6]=ss;
  __syncthreads();
  if(threadIdx.x==0) nrm[r] = sqrtf(sm[0]+sm[1]+sm[2]+sm[3]);
}

__global__ __launch_bounds__(256) void k_row_norm_bf16(const u16* __restrict__ z,
    float* __restrict__ nrm, int K){
  int r = blockIdx.x;
  const u16* row = z + (size_t)r*K;
  float ss=0.f;
  for(int d=threadIdx.x; d<K; d+=256){ float x=bf2f(row[d]); ss+=x*x; }
  ss = wred_sum(ss);
  __shared__ float sm[4];
  if((threadIdx.x&63)==0) sm[threadIdx.x>>6]=ss;
  __syncthreads();
  if(threadIdx.x==0) nrm[r] = sqrtf(sm[0]+sm[1]+sm[2]+sm[3]);
}

// W (HSS x HTT) f32 -> Wt (HTT x HSS) bf16
__global__ void k_wt(const float* __restrict__ W, u16* __restrict__ Wt){
  __shared__ float t[32][33];
  int k0 = blockIdx.y*32, n0 = blockIdx.x*32;
  int tx = threadIdx.x, ty = threadIdx.y;
  for(int r=0;r<32;r+=8) t[ty+r][tx] = W[(size_t)(k0+ty+r)*HTT + n0+tx];
  __syncthreads();
  for(int r=0;r<32;r+=8) Wt[(size_t)(n0+ty+r)*HSS + k0+tx] = f2bf(t[tx][ty+r]);
}

// fused saliency: blocks 0..63 -> (ns -> mu), 64..127 -> (nt -> nu)
__global__ __launch_bounds__(256) void k_saliency2(const float* __restrict__ ns,
    const float* __restrict__ nt, float* __restrict__ omu, float* __restrict__ onu){
  int b0 = blockIdx.x, n = threadIdx.x;
  const float* nrm = (b0 < NB) ? ns : nt;
  float* out = (b0 < NB) ? omu : onu;
  int b = b0 & 63;
  float x = nrm[b*NN+n];
  float mx = wred_max(x);
  __shared__ float sm[4], sm2[4];
  if((n&63)==0) sm[n>>6]=mx;
  __syncthreads();
  mx = fmaxf(fmaxf(sm[0],sm[1]),fmaxf(sm[2],sm[3]));
  float e = expf(x-mx);
  float s = wred_sum(e);
  if((n&63)==0) sm2[n>>6]=s;
  __syncthreads();
  s = sm2[0]+sm2[1]+sm2[2]+sm2[3];
  out[b*NN+n] = e/s;
}

// ---------------- MFMA GEMM (NT form) ----------------
enum { MODE_PROJ=0, MODE_COST=1, MODE_PLAIN=2, MODE_STRUCT=3 };

template<int MODE>
__global__ __launch_bounds__(256) void k_mfma(
    const u16* __restrict__ A, int lda, long bA,
    const u16* __restrict__ B, int ldb, long bB,
    int K,
    float* __restrict__ outF, u16* __restrict__ outB, int ldo, long bO,
    const float* __restrict__ nx, const float* __restrict__ ny,
    const float* __restrict__ bias,
    const float* __restrict__ Cs, const float* __restrict__ mu,
    float* __restrict__ accp)
{
  __shared__ u16 As[128*32];
  __shared__ u16 Bs[128*32];
  __shared__ float red[4];

  // XCD-aware bijective block swizzle (all grids have nwg % 8 == 0)
  int gx = gridDim.x, gy = gridDim.y;
  int flat = blockIdx.x + gx*(blockIdx.y + gy*blockIdx.z);
  int nwg  = gx*gy*gridDim.z;
  int cpx  = nwg >> 3;
  int lg   = (flat & 7)*cpx + (flat >> 3);
  int bx   = lg % gx;
  int rest = lg / gx;
  int by   = rest % gy;
  int b    = rest / gy;

  const u16* Ab = A + (size_t)b*bA;
  const u16* Bb = B + (size_t)b*bB;
  int tid = threadIdx.x;
  int lane = tid & 63, w = tid >> 6;
  int m0 = by*128, n0 = bx*128;
  int row_off = (w>>1)*64, col_off = (w&1)*64;
  int q = lane>>4, loc = lane&15;
  f32x4 acc[4][4] = {};

  const int srow = (lane >> 2);
  const int sslot = lane & 3;

  for(int k0=0;k0<K;k0+=32){
    #pragma unroll
    for(int h=0;h<2;h++){
      int row = h*64 + w*16 + srow;
      int ca  = (sslot ^ ((row>>1)&3))*8;            // inverse of read-side XOR
      u16* ldst = As + h*2048 + w*512 + lane*8;      // linear: row*32 + slot*8
      u16* ldstB= Bs + h*2048 + w*512 + lane*8;
      gl16(Ab + (size_t)(m0+row)*lda + k0 + ca, ldst);
      gl16(Bb + (size_t)(n0+row)*ldb + k0 + ca, ldstB);
    }
    __syncthreads();
    bf16x8 af[4], bfr[4];
    #pragma unroll
    for(int mi=0;mi<4;mi++){
      int r = row_off + mi*16 + loc;
      int slot = q ^ ((r>>1)&3);
      af[mi] = *(const bf16x8*)(As + r*32 + slot*8);
    }
    #pragma unroll
    for(int ni=0;ni<4;ni++){
      int r = col_off + ni*16 + loc;
      int slot = q ^ ((r>>1)&3);
      bfr[ni] = *(const bf16x8*)(Bs + r*32 + slot*8);
    }
    #pragma unroll
    for(int mi=0;mi<4;mi++)
      #pragma unroll
      for(int ni=0;ni<4;ni++)
        acc[mi][ni] = __builtin_amdgcn_mfma_f32_16x16x32_bf16(af[mi], bfr[ni], acc[mi][ni], 0,0,0);
    __syncthreads();
  }

  float* outFb = outF ? outF + (size_t)b*bO : nullptr;
  u16*   outBb = outB ? outB + (size_t)b*bO : nullptr;
  const float* nxb = nx ? nx + (size_t)b*NN : nullptr;
  const float* nyb = ny ? ny + (size_t)b*NN : nullptr;
  const float* Cb  = (MODE==MODE_STRUCT) ? Cs + (size_t)b*bO : nullptr;
  const float* mb  = (MODE==MODE_STRUCT) ? mu + (size_t)b*NN : nullptr;
  float lsum = 0.f;
  #pragma unroll
  for(int mi=0;mi<4;mi++){
    #pragma unroll
    for(int j=0;j<4;j++){
      int row = m0 + row_off + mi*16 + q*4 + j;
      float ir = 0.f, mr = 0.f;
      if(MODE==MODE_COST)   ir = 1.f/fmaxf(nxb[row],1e-12f);
      if(MODE==MODE_STRUCT) mr = mb[row];
      #pragma unroll
      for(int ni=0;ni<4;ni++){
        int col = n0 + col_off + ni*16 + loc;
        float v = acc[mi][ni][j];
        if(MODE==MODE_PROJ){
          v += bias[col];
          outBb[(size_t)row*ldo + col] = f2bf(v);
        } else if(MODE==MODE_COST){
          float ic = 1.f/fmaxf(nyb[col],1e-12f);
          v = 1.f - v*ir*ic;
          if(outFb) outFb[(size_t)row*ldo + col] = v;
          if(outBb) outBb[(size_t)row*ldo + col] = f2bf(v);
        } else if(MODE==MODE_PLAIN){
          outBb[(size_t)row*ldo + col] = f2bf(v);
        } else {
          float d = Cb[(size_t)row*ldo + col] - v;
          lsum += d*d*mr*mb[col];
        }
      }
    }
  }
  if(MODE==MODE_STRUCT){
    lsum = wred_sum(lsum);
    if(lane==0) red[w] = lsum;
    __syncthreads();
    if(tid==0) atomicAdd(accp+6, red[0]+red[1]+red[2]+red[3]);
  }
}

// ---------------- fused Sinkhorn: 2 phases / 2 barriers per iteration ----------------
// u and v updates are computed INLINE in the consuming phase (per-wave, no extra barrier):
//  - row phase: each wave's 64 lanes own exactly the 64 cols it dots; lane l reduces
//    the 16 partB strip-partials for col cl, divides, parks v in a wave-private LDS slot.
//  - col phase: lane (l&15) reduces the 4 row-partials for strip row rw, divides;
//    broadcast across the wave via v_readlane.
// Summation order identical to the 4-phase version -> numerically unchanged.
#define SINK_DYN_LDS 131072
__global__ __launch_bounds__(1024, 1) void k_sinkhorn_fused(
    const u16* __restrict__ Mbf, const float* __restrict__ muL,
    const float* __restrict__ nuL, u16* __restrict__ Gn, float* __restrict__ accp)
{
  extern __shared__ u16 Ks[];                        // 256x256 bf16, swizzled
  __shared__ __align__(16) float partA[1024];        // row partials (4 per row)
  __shared__ __align__(16) float partB[4096];        // col strip partials (16 x 256)
  __shared__ __align__(16) float svw[1024];          // wave-private v scratch / epilogue row partials
  __shared__ __align__(16) float smu_s[256], snu_s[256], sv_ep[256];
  __shared__ float red[16];

  const int b = blockIdx.x;
  const int t = threadIdx.x;
  const u16* Mb = Mbf + (size_t)b*NN*NN;

  #pragma unroll
  for(int i=0;i<16;i++){
    int e = (i*1024 + t)*4;
    int r = e>>8, c = e&255;
    ushort4 mv = *(const ushort4*)(Mb + e);
    ushort4 o;
    o.x = f2bf(exp2f(-C2LOG*bf2f(mv.x)));
    o.y = f2bf(exp2f(-C2LOG*bf2f(mv.y)));
    o.z = f2bf(exp2f(-C2LOG*bf2f(mv.z)));
    o.w = f2bf(exp2f(-C2LOG*bf2f(mv.w)));
    *(ushort4*)(Ks + LIDX(r,c)) = o;
  }
  if(t < NN){
    smu_s[t] = muL[(size_t)b*NN+t] + 1e-8f;
    snu_s[t] = nuL[(size_t)b*NN+t] + 1e-8f;
  }
  __syncthreads();

  const int w = t>>6, l = t&63;
  const int r_ = t & 255, p_ = t >> 8;     // row-phase mapping
  const int rw = (w<<4) + (l&15);          // col-phase strip row
  const int cl = (p_<<6) + l;              // this lane's v column
  float* svslot = svw + (w<<6);

  #pragma unroll 1
  for(int it=0; it<21; it++){
    // ---- row phase: S_r = sum_c K[r,c] * v[c], v inline from partB ----
    float vl;
    if(it==0){ vl = 1.f; }
    else {
      float Tc = 0.f;
      #pragma unroll
      for(int ww=0; ww<16; ww++) Tc += partB[(ww<<8) + cl];
      vl = snu_s[cl] / Tc;
    }
    svslot[l] = vl;
    if(it==20 && (w&3)==0) sv_ep[cl] = vl;   // final v for the output phase
    float sacc = 0.f;
    #pragma unroll
    for(int jj=0;jj<8;jj++){
      int c0 = (p_<<6) + (jj<<3);
      uint4 kv = *(const uint4*)(Ks + LIDX(r_, c0));
      float4 va = *(const float4*)(svslot + (jj<<3));
      float4 vb = *(const float4*)(svslot + (jj<<3) + 4);
      sacc += __uint_as_float(kv.x<<16)          * va.x;
      sacc += __uint_as_float(kv.x & 0xffff0000u)* va.y;
      sacc += __uint_as_float(kv.y<<16)          * va.z;
      sacc += __uint_as_float(kv.y & 0xffff0000u)* va.w;
      sacc += __uint_as_float(kv.z<<16)          * vb.x;
      sacc += __uint_as_float(kv.z & 0xffff0000u)* vb.y;
      sacc += __uint_as_float(kv.w<<16)          * vb.z;
      sacc += __uint_as_float(kv.w & 0xffff0000u)* vb.w;
    }
    if(it==20) svw[t] = sacc;   // epilogue row sums (wave-private slot, reads done)
    else       partA[t] = sacc;
    __syncthreads();
    if(it==20) break;

    // ---- col phase: T_c = sum_r K[r,c] * u[r], u inline from partA ----
    float S = partA[rw] + partA[256+rw] + partA[512+rw] + partA[768+rw];
    float ul = smu_s[rw] / S;
    float cs0=0.f,cs1=0.f,cs2=0.f,cs3=0.f;
    #pragma unroll
    for(int rr=0; rr<16; rr++){
      float ur = rdlane(ul, rr);
      ushort4 kv = *(const ushort4*)(Ks + LIDX((w<<4)+rr, l<<2));
      cs0 = fmaf(bf2f(kv.x), ur, cs0);
      cs1 = fmaf(bf2f(kv.y), ur, cs1);
      cs2 = fmaf(bf2f(kv.z), ur, cs2);
      cs3 = fmaf(bf2f(kv.w), ur, cs3);
    }
    float4 o; o.x=cs0; o.y=cs1; o.z=cs2; o.w=cs3;
    *(float4*)(partB + (w<<8) + (l<<2)) = o;
    __syncthreads();
  }

  // ---- output phase (strip-shaped): Gamma, Gn, feat loss ----
  // partA holds (K v_19) row sums -> u_20; svw holds (K v_20) row sums.
  float Sold = partA[rw] + partA[256+rw] + partA[512+rw] + partA[768+rw];
  float ul   = smu_s[rw] / Sold;
  float Snew = svw[rw] + svw[256+rw] + svw[512+rw] + svw[768+rw];
  float invl = 1.f / (ul*Snew + 1e-8f);

  u16* Gb = Gn + (size_t)b*NN*NN;
  const float IC = -1.f/C2LOG;
  float4 v4 = *(const float4*)(sv_ep + (l<<2));
  float fl = 0.f;
  #pragma unroll
  for(int rr=0; rr<16; rr++){
    int r = (w<<4) + rr;
    float ur  = rdlane(ul, rr);
    float inv = rdlane(invl, rr);
    ushort4 kv = *(const ushort4*)(Ks + LIDX(r, l<<2));
    float k0=bf2f(kv.x), k1=bf2f(kv.y), k2=bf2f(kv.z), k3=bf2f(kv.w);
    float g0=ur*k0*v4.x, g1=ur*k1*v4.y, g2=ur*k2*v4.z, g3=ur*k3*v4.w;
    fl += g0*(__log2f(k0)*IC) + g1*(__log2f(k1)*IC)
        + g2*(__log2f(k2)*IC) + g3*(__log2f(k3)*IC);
    ushort4 o;
    o.x=f2bf(g0*inv); o.y=f2bf(g1*inv); o.z=f2bf(g2*inv); o.w=f2bf(g3*inv);
    *(ushort4*)(Gb + (size_t)r*NN + (l<<2)) = o;
  }
  fl = wred_sum(fl);
  if(l==0) red[w] = fl;
  __syncthreads();
  if(t==0){
    float s=0.f;
    #pragma unroll
    for(int i=0;i<16;i++) s+=red[i];
    atomicAdd(accp+5, s);
  }
}

__global__ void k_final(const float* __restrict__ acc, float* __restrict__ out){
  out[0] = acc[0]
         + 20.f*acc[3]*(1.f/8128.f)
         + 40.f*acc[4]*(1.f/2048256.f)
         + 0.25f*(acc[5]+acc[6])*(1.f/64.f);
}

// ---------------- host ----------------
extern "C" void kernel_launch(void* const* d_in, const int* in_sizes, int n_in,
                              void* d_out, int out_size, void* d_ws, size_t ws_size,
                              hipStream_t stream) {
  const float* s_q_reps   = (const float*)d_in[0];
  const float* s_p_reps   = (const float*)d_in[1];
  const float* t_q_reps   = (const float*)d_in[2];
  const float* t_p_reps   = (const float*)d_in[3];
  const float* s_q_states = (const float*)d_in[4];
  const float* s_p_states = (const float*)d_in[5];
  const float* t_q_states = (const float*)d_in[6];
  const float* t_p_states = (const float*)d_in[7];
  const float* proj_w     = (const float*)d_in[8];
  const float* proj_b     = (const float*)d_in[9];
  float* ws = (float*)d_ws;
  float* acc = ws + OFF_ACC;
  u16* M_BF   = (u16*)(ws + OFF_MBF);
  u16* ZS_BF  = (u16*)(ws + OFF_ZS_BF);
  u16* ZT_BF  = (u16*)(ws + OFF_ZT_BF);
  u16* WT_BF  = (u16*)(ws + OFF_WT_BF);
  u16* ZSP_BF = (u16*)(ws + OFF_ZSP_BF);
  u16* GN_BF  = (u16*)(ws + OFF_GN_BF);
  u16* CT_BF  = (u16*)(ws + OFF_CT_BF);
  u16* T_BF   = (u16*)(ws + OFF_T_BF);

  hipFuncSetAttribute(reinterpret_cast<const void*>(k_sinkhorn_fused),
                      hipFuncAttributeMaxDynamicSharedMemorySize, SINK_DYN_LDS);
  hipFuncSetAttribute(reinterpret_cast<const void*>(k_rkd_angle_mfma),
                      hipFuncAttributeMaxDynamicSharedMemorySize, RKD_LDS);

  hipMemsetAsync(acc, 0, 16*sizeof(float), stream);

  // ---- Part A ----
  k_l2norm_all<<<384,256,0,stream>>>(s_q_reps, s_p_reps, t_q_reps, t_p_reps, ws);
  k_contrastive2<<<128,512,0,stream>>>(ws, acc);
  k_gram_ds<<<128,128,0,stream>>>(ws+OFF_SQ128, ws+OFF_TQ128, ws+OFF_DS, ws+OFF_DT, acc);
  k_rkd_dist<<<128,128,0,stream>>>(ws+OFF_DS, ws+OFF_DT, acc);
  k_rkd_angle_mfma<<<256,256,RKD_LDS,stream>>>(ws+OFF_SQ128, ws+OFF_TQ128, acc);

  k_wt<<<dim3(HTT/32, HSS/32),dim3(32,8),0,stream>>>(proj_w, WT_BF);

  // ---- Part B phase 1: per-pass GEMMs into doubled buffers ----
  for(int pass=0; pass<2; pass++){
    const float* zs = pass ? s_p_states : s_q_states;
    const float* zt = pass ? t_p_states : t_q_states;
    size_t po  = (size_t)pass*NB*NN*NN;
    size_t pr  = (size_t)pass*ROWS;
    k_cvt_norm<<<ROWS,256,0,stream>>>(zs, ZS_BF, ws+OFF_NS, HSS);
    k_cvt_norm<<<ROWS,256,0,stream>>>(zt, ZT_BF, ws+OFF_NT, HTT);
    k_saliency2<<<128,256,0,stream>>>(ws+OFF_NS, ws+OFF_NT, ws+OFF_MU+pr, ws+OFF_NU+pr);
    k_mfma<MODE_PROJ><<<dim3(HTT/128, ROWS/128, 1),256,0,stream>>>(
        ZS_BF, HSS, 0, WT_BF, HSS, 0, HSS,
        nullptr, ZSP_BF, HTT, 0,
        nullptr, nullptr, proj_b, nullptr, nullptr, nullptr);
    k_row_norm_bf16<<<ROWS,256,0,stream>>>(ZSP_BF, ws+OFF_NSP, HTT);
    // C_s (f32)
    k_mfma<MODE_COST><<<dim3(2,2,NB),256,0,stream>>>(
        ZS_BF, HSS, (long)NN*HSS, ZS_BF, HSS, (long)NN*HSS, HSS,
        ws+OFF_CS+po, nullptr, NN, (long)NN*NN,
        ws+OFF_NS, ws+OFF_NS, nullptr, nullptr, nullptr, nullptr);
    // C_t (bf16)
    k_mfma<MODE_COST><<<dim3(2,2,NB),256,0,stream>>>(
        ZT_BF, HTT, (long)NN*HTT, ZT_BF, HTT, (long)NN*HTT, HTT,
        nullptr, CT_BF+po, NN, (long)NN*NN,
        ws+OFF_NT, ws+OFF_NT, nullptr, nullptr, nullptr, nullptr);
    // M (bf16)
    k_mfma<MODE_COST><<<dim3(2,2,NB),256,0,stream>>>(
        ZSP_BF, HTT, (long)NN*HTT, ZT_BF, HTT, (long)NN*HTT, HTT,
        nullptr, M_BF+po, NN, (long)NN*NN,
        ws+OFF_NSP, ws+OFF_NT, nullptr, nullptr, nullptr, nullptr);
  }

  // ---- Part B phase 2: Sinkhorn (both passes, multiplicative, K in LDS) ----
  k_sinkhorn_fused<<<2*NB,1024,SINK_DYN_LDS,stream>>>(
      M_BF, ws+OFF_MU, ws+OFF_NU, GN_BF, acc);

  // ---- Part B phase 3: T = Gn@Ct, struct loss (batched over both passes) ----
  k_mfma<MODE_PLAIN><<<dim3(2,2,2*NB),256,0,stream>>>(
      GN_BF, NN, (long)NN*NN, CT_BF, NN, (long)NN*NN, NN,
      nullptr, T_BF, NN, (long)NN*NN,
      nullptr, nullptr, nullptr, nullptr, nullptr, nullptr);
  k_mfma<MODE_STRUCT><<<dim3(2,2,2*NB),256,0,stream>>>(
      T_BF, NN, (long)NN*NN, GN_BF, NN, (long)NN*NN, NN,
      nullptr, nullptr, NN, (long)NN*NN,
      nullptr, nullptr, nullptr, ws+OFF_CS, ws+OFF_MU, acc);

  k_final<<<1,1,0,stream>>>(acc, (float*)d_out);
}

// Round 4
// 680.023 us; speedup vs baseline: 1.2657x; 1.0565x over previous
//
#include <hip/hip_runtime.h>
#include <math.h>

// Problem dims
#define NB   64      // batch B
#define NN   256     // tokens N
#define HSS  768     // H_S
#define HTT  1024    // H_T
#define ROWS (NB*NN) // 16384
#define C2LOG 14.426950408889634f  // 10 * log2(e)

typedef unsigned short u16;
typedef __attribute__((ext_vector_type(8))) short bf16x8;
typedef __attribute__((ext_vector_type(4))) float f32x4;

// swizzled LDS index for K[r][c] (256 cols): chunk rotation, 8-u16 granularity
#define LIDX(r,c) (((r)<<8) + (((((c)>>3) + (r)) & 31)<<3) + ((c)&7))
// swizzled LDS index for E[r][c] (128 cols, 16 chunks of 8)
#define EIDX(r,c) (((r)<<7) + (((((c)>>3) + (r)) & 15)<<3) + ((c)&7))

// async global->LDS, 16B per lane (gfx950)
__device__ __forceinline__ void gl16(const u16* g, u16* l){
  __builtin_amdgcn_global_load_lds(
      (const __attribute__((address_space(1))) unsigned int*)g,
      (__attribute__((address_space(3))) unsigned int*)l,
      16, 0, 0);
}

// ---------------- workspace layout (float offsets) ----------------
static const size_t OFF_ACC   = 0;                          // 16 floats
static const size_t OFF_SQ128 = 16;
static const size_t OFF_SP128 = OFF_SQ128 + 64*128;
static const size_t OFF_TQ128 = OFF_SP128 + 64*128;
static const size_t OFF_TP128 = OFF_TQ128 + 64*128;
static const size_t OFF_SQ768 = OFF_TP128 + 64*128;
static const size_t OFF_SP768 = OFF_SQ768 + 64*768;
static const size_t OFF_DS    = OFF_SP768 + 64*768;         // 128*128
static const size_t OFF_DT    = OFF_DS + 128*128;
static const size_t OFF_CS    = OFF_DT + 128*128;           // 2*B*N*N f32
static const size_t OFF_MBF   = OFF_CS  + (size_t)2*NB*NN*NN;     // 2*B*N*N bf16
static const size_t OFF_ZS_BF = OFF_MBF + (size_t)NB*NN*NN;       // 16384x768 bf16
static const size_t OFF_ZT_BF = OFF_ZS_BF + (size_t)ROWS*HSS/2;   // 16384x1024 bf16
static const size_t OFF_WT_BF = OFF_ZT_BF + (size_t)ROWS*HTT/2;   // 1024x768 bf16
static const size_t OFF_ZSP_BF= OFF_WT_BF + (size_t)HTT*HSS/2;    // 16384x1024 bf16
static const size_t OFF_GN_BF = OFF_ZSP_BF+ (size_t)ROWS*HTT/2;   // 2*B*N*N bf16
static const size_t OFF_CT_BF = OFF_GN_BF + (size_t)NB*NN*NN;     // 2*B*N*N bf16
static const size_t OFF_T_BF  = OFF_ZS_BF;                  // ALIAS: ZS dead after cost GEMMs
static const size_t OFF_NS    = OFF_CT_BF + (size_t)NB*NN*NN;
static const size_t OFF_NT    = OFF_NS + ROWS;
static const size_t OFF_NSP   = OFF_NT + ROWS;
static const size_t OFF_MU    = OFF_NSP + ROWS;             // 2*ROWS (linear)
static const size_t OFF_NU    = OFF_MU + 2*ROWS;            // 2*ROWS (linear)

// acc: 0=contrastive 1=ds_sum 2=dt_sum 3=dist_huber 4=angle_huber 5=feat 6=struct

// ---------------- helpers ----------------
__device__ __forceinline__ float wred_sum(float v){
  #pragma unroll
  for(int o=32;o>0;o>>=1) v += __shfl_xor(v,o,64);
  return v;
}
__device__ __forceinline__ float wred_max(float v){
  #pragma unroll
  for(int o=32;o>0;o>>=1) v = fmaxf(v, __shfl_xor(v,o,64));
  return v;
}
__device__ __forceinline__ u16 f2bf(float f){
  unsigned u = __float_as_uint(f);
  unsigned r = (u + 0x7fffu + ((u>>16)&1u)) >> 16;
  return (u16)r;
}
__device__ __forceinline__ float bf2f(u16 h){
  return __uint_as_float(((unsigned)h)<<16);
}
__device__ __forceinline__ float rdlane(float v, int srcLane){
  return __uint_as_float(__builtin_amdgcn_readlane(__float_as_uint(v), srcLane));
}

// ---------------- Part A kernels ----------------
// fused 6-way l2norm: blocks 0..255 -> 128-dim slices of {sq,sp,tq,tp};
// blocks 256..383 -> 768-dim of {sq,sp}
__global__ __launch_bounds__(256) void k_l2norm_all(
    const float* __restrict__ sq, const float* __restrict__ sp,
    const float* __restrict__ tq, const float* __restrict__ tp,
    float* __restrict__ ws){
  int bid = blockIdx.x;
  int r = bid & 63;
  const float* in; float* out; int kuse;
  if(bid < 64)       { in = sq; out = ws + OFF_SQ128; kuse = 128; }
  else if(bid < 128) { in = sp; out = ws + OFF_SP128; kuse = 128; }
  else if(bid < 192) { in = tq; out = ws + OFF_TQ128; kuse = 128; }
  else if(bid < 256) { in = tp; out = ws + OFF_TP128; kuse = 128; }
  else if(bid < 320) { in = sq; out = ws + OFF_SQ768; kuse = 768; }
  else               { in = sp; out = ws + OFF_SP768; kuse = 768; }
  const float* row = in + (size_t)r*768;
  float ss = 0.f;
  for(int d=threadIdx.x; d<kuse; d+=256){ float x=row[d]; ss += x*x; }
  ss = wred_sum(ss);
  __shared__ float sm[4];
  if((threadIdx.x&63)==0) sm[threadIdx.x>>6]=ss;
  __syncthreads();
  float tot = sm[0]+sm[1]+sm[2]+sm[3];
  float inv = 1.f / fmaxf(sqrtf(tot), 1e-12f);
  for(int d=threadIdx.x; d<kuse; d+=256) out[(size_t)r*kuse + d] = row[d]*inv;
}

// fused contrastive (both matryoshka dims): blocks 0..63 dim=128 w=1, 64..127 dim=768 w=2
__global__ __launch_bounds__(512) void k_contrastive2(const float* __restrict__ ws,
    float* __restrict__ acc){
  int bid = blockIdx.x;
  int i = bid & 63;
  int big = bid >> 6;
  const float* q = ws + (big ? OFF_SQ768 : OFF_SQ128);
  const float* p = ws + (big ? OFF_SP768 : OFF_SP128);
  int dim = big ? 768 : 128;
  float weight = big ? 2.f : 1.f;
  int j = threadIdx.x & 63;
  int part = threadIdx.x >> 6;           // 0..7
  const float* qi = q + (size_t)i*dim;
  const float* pj = p + (size_t)j*dim;
  int seg = dim >> 3;
  int d0 = part*seg;
  float dot = 0.f;
  for(int d=d0; d<d0+seg; d+=4){
    float4 a = *(const float4*)(qi+d);
    float4 b = *(const float4*)(pj+d);
    dot = fmaf(a.x,b.x,dot);
    dot = fmaf(a.y,b.y,dot);
    dot = fmaf(a.z,b.z,dot);
    dot = fmaf(a.w,b.w,dot);
  }
  __shared__ float sm[8][64];
  sm[part][j] = dot;
  __syncthreads();
  if(part==0){
    float s = 0.f;
    #pragma unroll
    for(int k=0;k<8;k++) s += sm[k][j];
    s = s / 0.07f;
    float mx = wred_max(s);
    float e = expf(s - mx);
    float Z = wred_sum(e);
    float logZ = mx + logf(Z);
    float diag = __shfl(s, i, 64);
    if(j==0) atomicAdd(acc+0, weight*(logZ - diag)*(1.f/64.f));
  }
}

__global__ __launch_bounds__(128) void k_gram_ds(const float* __restrict__ sb,
    const float* __restrict__ tb, float* __restrict__ ds, float* __restrict__ dt,
    float* __restrict__ acc){
  int r = blockIdx.x, c = threadIdx.x;
  const float* sr = sb + r*128; const float* sc = sb + c*128;
  const float* tr = tb + r*128; const float* tc = tb + c*128;
  float dot_s=0,ssr=0,ssc=0,dot_t=0,tsr=0,tsc=0;
  for(int d=0; d<128; d++){
    float a=sr[d], b=sc[d]; dot_s += a*b; ssr += a*a; ssc += b*b;
    float at=tr[d], bt=tc[d]; dot_t += at*bt; tsr += at*at; tsc += bt*bt;
  }
  float dv = ssr + ssc - 2.f*dot_s;
  float tv = tsr + tsc - 2.f*dot_t;
  ds[r*128+c] = dv; dt[r*128+c] = tv;
  float ms = (c>r)? dv : 0.f;
  float mt = (c>r)? tv : 0.f;
  ms = wred_sum(ms); mt = wred_sum(mt);
  __shared__ float sm[2][2];
  if((threadIdx.x&63)==0){ sm[0][threadIdx.x>>6]=ms; sm[1][threadIdx.x>>6]=mt; }
  __syncthreads();
  if(threadIdx.x==0){ atomicAdd(acc+1, sm[0][0]+sm[0][1]); atomicAdd(acc+2, sm[1][0]+sm[1][1]); }
}

__global__ __launch_bounds__(128) void k_rkd_dist(const float* __restrict__ ds,
    const float* __restrict__ dt, float* __restrict__ acc){
  int r=blockIdx.x, c=threadIdx.x;
  float mean_s = acc[1]*(1.f/8128.f) + 1e-8f;
  float mean_t = acc[2]*(1.f/8128.f) + 1e-8f;
  float h=0.f;
  if(c>r){
    float diff = ds[r*128+c]/mean_s - dt[r*128+c]/mean_t;
    float a = fabsf(diff);
    h = (a<1.f)? 0.5f*a*a : a-0.5f;
  }
  h = wred_sum(h);
  __shared__ float sm[2];
  if((threadIdx.x&63)==0) sm[threadIdx.x>>6]=h;
  __syncthreads();
  if(threadIdx.x==0) atomicAdd(acc+3, sm[0]+sm[1]);
}

// ---- RKD angle via MFMA: psi = E E^T, E in bf16 LDS, huber fused ----
#define RKD_LDS 65536
__global__ __launch_bounds__(256, 1) void k_rkd_angle_mfma(
    const float* __restrict__ sb, const float* __restrict__ tb,
    float* __restrict__ accp)
{
  extern __shared__ u16 eSh[];
  u16* Es = eSh;
  u16* Et = eSh + 128*128;
  const int j    = blockIdx.x >> 1;
  const int half = blockIdx.x & 1;
  const int tid = threadIdx.x;
  {
    const int i = tid >> 1, h = tid & 1;
    #pragma unroll
    for(int which=0; which<2; which++){
      const float* xb = which ? tb : sb;
      u16* E = which ? Et : Es;
      const float* xj = xb + j*128 + h*64;
      const float* xi = xb + i*128 + h*64;
      float ss = 0.f;
      #pragma unroll
      for(int d4=0; d4<16; d4++){
        float4 a = *(const float4*)(xj + d4*4);
        float4 b = *(const float4*)(xi + d4*4);
        float d0=a.x-b.x, d1=a.y-b.y, d2=a.z-b.z, d3=a.w-b.w;
        ss += d0*d0+d1*d1+d2*d2+d3*d3;
      }
      ss += __shfl_xor(ss, 1, 64);
      float inv = (i==j) ? 0.f : 1.f/(sqrtf(ss)+1e-8f);
      #pragma unroll
      for(int d4=0; d4<16; d4++){
        float4 a = *(const float4*)(xj + d4*4);
        float4 b = *(const float4*)(xi + d4*4);
        int c = h*64 + d4*4;
        E[EIDX(i,c+0)] = f2bf((a.x-b.x)*inv);
        E[EIDX(i,c+1)] = f2bf((a.y-b.y)*inv);
        E[EIDX(i,c+2)] = f2bf((a.z-b.z)*inv);
        E[EIDX(i,c+3)] = f2bf((a.w-b.w)*inv);
      }
    }
  }
  __syncthreads();
  const int w = tid >> 6, lane = tid & 63;
  const int q = lane >> 4, loc = lane & 15;
  float hsum = 0.f;
  #pragma unroll
  for(int ni=0; ni<4; ni++){
    const int cb = half*64 + ni*16;
    #pragma unroll
    for(int mi=0; mi<2; mi++){
      const int rb = w*32 + mi*16;
      f32x4 as_ = {0.f,0.f,0.f,0.f}, at_ = {0.f,0.f,0.f,0.f};
      #pragma unroll
      for(int k0=0; k0<128; k0+=32){
        int ra = rb + loc, rbn = cb + loc;
        int ca = k0 + q*8;
        bf16x8 aS = *(const bf16x8*)(Es + EIDX(ra, ca));
        bf16x8 bS = *(const bf16x8*)(Es + EIDX(rbn, ca));
        bf16x8 aT = *(const bf16x8*)(Et + EIDX(ra, ca));
        bf16x8 bT = *(const bf16x8*)(Et + EIDX(rbn, ca));
        as_ = __builtin_amdgcn_mfma_f32_16x16x32_bf16(aS, bS, as_, 0,0,0);
        at_ = __builtin_amdgcn_mfma_f32_16x16x32_bf16(aT, bT, at_, 0,0,0);
      }
      #pragma unroll
      for(int jj=0; jj<4; jj++){
        int row = rb + q*4 + jj, col = cb + loc;
        if(row != col){
          float d = as_[jj] - at_[jj];
          float a = fabsf(d);
          hsum += (a < 1.f) ? 0.5f*a*a : a - 0.5f;
        }
      }
    }
  }
  hsum = wred_sum(hsum);
  __syncthreads();
  float* red = (float*)eSh;
  if(lane==0) red[w] = hsum;
  __syncthreads();
  if(tid==0) atomicAdd(accp+4, red[0]+red[1]+red[2]+red[3]);
}

// ---------------- Part B: convert+norm / saliency ----------------
// wave-per-row: grid ROWS/4 x 256 thr. float4 loads, no LDS, no block sync.
__global__ __launch_bounds__(256) void k_cvt_norm(const float* __restrict__ in,
    u16* __restrict__ out, float* __restrict__ nrm, int K){
  int w = threadIdx.x >> 6, l = threadIdx.x & 63;
  int r = blockIdx.x*4 + w;
  const float* row = in + (size_t)r*K;
  u16* orow = out + (size_t)r*K;
  float ss = 0.f;
  int nv = K >> 8;                      // float4 per lane: 3 (K=768) or 4 (K=1024)
  for(int i=0;i<nv;i++){
    int d = l*4 + i*256;
    float4 x = *(const float4*)(row + d);
    ushort4 o; o.x=f2bf(x.x); o.y=f2bf(x.y); o.z=f2bf(x.z); o.w=f2bf(x.w);
    *(ushort4*)(orow + d) = o;
    ss += x.x*x.x + x.y*x.y + x.z*x.z + x.w*x.w;
  }
  ss = wred_sum(ss);
  if(l==0) nrm[r] = sqrtf(ss);
}

// wave-per-row bf16 row norms (K multiple of 512): uint4 = 8 bf16 per load
__global__ __launch_bounds__(256) void k_row_norm_bf16(const u16* __restrict__ z,
    float* __restrict__ nrm, int K){
  int w = threadIdx.x >> 6, l = threadIdx.x & 63;
  int r = blockIdx.x*4 + w;
  const u16* row = z + (size_t)r*K;
  float ss = 0.f;
  int nv = K >> 9;                      // uint4 per lane: 2 (K=1024)
  for(int i=0;i<nv;i++){
    int d = l*8 + i*512;
    uint4 v = *(const uint4*)(row + d);
    float a0=__uint_as_float(v.x<<16), a1=__uint_as_float(v.x&0xffff0000u);
    float a2=__uint_as_float(v.y<<16), a3=__uint_as_float(v.y&0xffff0000u);
    float a4=__uint_as_float(v.z<<16), a5=__uint_as_float(v.z&0xffff0000u);
    float a6=__uint_as_float(v.w<<16), a7=__uint_as_float(v.w&0xffff0000u);
    ss += a0*a0+a1*a1+a2*a2+a3*a3+a4*a4+a5*a5+a6*a6+a7*a7;
  }
  ss = wred_sum(ss);
  if(l==0) nrm[r] = sqrtf(ss);
}

// W (HSS x HTT) f32 -> Wt (HTT x HSS) bf16
__global__ void k_wt(const float* __restrict__ W, u16* __restrict__ Wt){
  __shared__ float t[32][33];
  int k0 = blockIdx.y*32, n0 = blockIdx.x*32;
  int tx = threadIdx.x, ty = threadIdx.y;
  for(int r=0;r<32;r+=8) t[ty+r][tx] = W[(size_t)(k0+ty+r)*HTT + n0+tx];
  __syncthreads();
  for(int r=0;r<32;r+=8) Wt[(size_t)(n0+ty+r)*HSS + k0+tx] = f2bf(t[tx][ty+r]);
}

// fused saliency: blocks 0..63 -> (ns -> mu), 64..127 -> (nt -> nu)
__global__ __launch_bounds__(256) void k_saliency2(const float* __restrict__ ns,
    const float* __restrict__ nt, float* __restrict__ omu, float* __restrict__ onu){
  int b0 = blockIdx.x, n = threadIdx.x;
  const float* nrm = (b0 < NB) ? ns : nt;
  float* out = (b0 < NB) ? omu : onu;
  int b = b0 & 63;
  float x = nrm[b*NN+n];
  float mx = wred_max(x);
  __shared__ float sm[4], sm2[4];
  if((n&63)==0) sm[n>>6]=mx;
  __syncthreads();
  mx = fmaxf(fmaxf(sm[0],sm[1]),fmaxf(sm[2],sm[3]));
  float e = expf(x-mx);
  float s = wred_sum(e);
  if((n&63)==0) sm2[n>>6]=s;
  __syncthreads();
  s = sm2[0]+sm2[1]+sm2[2]+sm2[3];
  out[b*NN+n] = e/s;
}

// ---------------- MFMA GEMM (NT form) ----------------
enum { MODE_PROJ=0, MODE_COST=1, MODE_PLAIN=2, MODE_STRUCT=3 };

template<int MODE>
__global__ __launch_bounds__(256) void k_mfma(
    const u16* __restrict__ A, int lda, long bA,
    const u16* __restrict__ B, int ldb, long bB,
    int K,
    float* __restrict__ outF, u16* __restrict__ outB, int ldo, long bO,
    const float* __restrict__ nx, const float* __restrict__ ny,
    const float* __restrict__ bias,
    const float* __restrict__ Cs, const float* __restrict__ mu,
    float* __restrict__ accp)
{
  __shared__ u16 As[128*32];
  __shared__ u16 Bs[128*32];
  __shared__ float red[4];

  // XCD-aware bijective block swizzle (all grids have nwg % 8 == 0)
  int gx = gridDim.x, gy = gridDim.y;
  int flat = blockIdx.x + gx*(blockIdx.y + gy*blockIdx.z);
  int nwg  = gx*gy*gridDim.z;
  int cpx  = nwg >> 3;
  int lg   = (flat & 7)*cpx + (flat >> 3);
  int bx   = lg % gx;
  int rest = lg / gx;
  int by   = rest % gy;
  int b    = rest / gy;

  const u16* Ab = A + (size_t)b*bA;
  const u16* Bb = B + (size_t)b*bB;
  int tid = threadIdx.x;
  int lane = tid & 63, w = tid >> 6;
  int m0 = by*128, n0 = bx*128;
  int row_off = (w>>1)*64, col_off = (w&1)*64;
  int q = lane>>4, loc = lane&15;
  f32x4 acc[4][4] = {};

  const int srow = (lane >> 2);
  const int sslot = lane & 3;

  for(int k0=0;k0<K;k0+=32){
    #pragma unroll
    for(int h=0;h<2;h++){
      int row = h*64 + w*16 + srow;
      int ca  = (sslot ^ ((row>>1)&3))*8;            // inverse of read-side XOR
      u16* ldst = As + h*2048 + w*512 + lane*8;      // linear: row*32 + slot*8
      u16* ldstB= Bs + h*2048 + w*512 + lane*8;
      gl16(Ab + (size_t)(m0+row)*lda + k0 + ca, ldst);
      gl16(Bb + (size_t)(n0+row)*ldb + k0 + ca, ldstB);
    }
    __syncthreads();
    bf16x8 af[4], bfr[4];
    #pragma unroll
    for(int mi=0;mi<4;mi++){
      int r = row_off + mi*16 + loc;
      int slot = q ^ ((r>>1)&3);
      af[mi] = *(const bf16x8*)(As + r*32 + slot*8);
    }
    #pragma unroll
    for(int ni=0;ni<4;ni++){
      int r = col_off + ni*16 + loc;
      int slot = q ^ ((r>>1)&3);
      bfr[ni] = *(const bf16x8*)(Bs + r*32 + slot*8);
    }
    #pragma unroll
    for(int mi=0;mi<4;mi++)
      #pragma unroll
      for(int ni=0;ni<4;ni++)
        acc[mi][ni] = __builtin_amdgcn_mfma_f32_16x16x32_bf16(af[mi], bfr[ni], acc[mi][ni], 0,0,0);
    __syncthreads();
  }

  float* outFb = outF ? outF + (size_t)b*bO : nullptr;
  u16*   outBb = outB ? outB + (size_t)b*bO : nullptr;
  const float* nxb = nx ? nx + (size_t)b*NN : nullptr;
  const float* nyb = ny ? ny + (size_t)b*NN : nullptr;
  const float* Cb  = (MODE==MODE_STRUCT) ? Cs + (size_t)b*bO : nullptr;
  const float* mb  = (MODE==MODE_STRUCT) ? mu + (size_t)b*NN : nullptr;
  float lsum = 0.f;
  #pragma unroll
  for(int mi=0;mi<4;mi++){
    #pragma unroll
    for(int j=0;j<4;j++){
      int row = m0 + row_off + mi*16 + q*4 + j;
      float ir = 0.f, mr = 0.f;
      if(MODE==MODE_COST)   ir = 1.f/fmaxf(nxb[row],1e-12f);
      if(MODE==MODE_STRUCT) mr = mb[row];
      #pragma unroll
      for(int ni=0;ni<4;ni++){
        int col = n0 + col_off + ni*16 + loc;
        float v = acc[mi][ni][j];
        if(MODE==MODE_PROJ){
          v += bias[col];
          outBb[(size_t)row*ldo + col] = f2bf(v);
        } else if(MODE==MODE_COST){
          float ic = 1.f/fmaxf(nyb[col],1e-12f);
          v = 1.f - v*ir*ic;
          if(outFb) outFb[(size_t)row*ldo + col] = v;
          if(outBb) outBb[(size_t)row*ldo + col] = f2bf(v);
        } else if(MODE==MODE_PLAIN){
          outBb[(size_t)row*ldo + col] = f2bf(v);
        } else {
          float d = Cb[(size_t)row*ldo + col] - v;
          lsum += d*d*mr*mb[col];
        }
      }
    }
  }
  if(MODE==MODE_STRUCT){
    lsum = wred_sum(lsum);
    if(lane==0) red[w] = lsum;
    __syncthreads();
    if(tid==0) atomicAdd(accp+6, red[0]+red[1]+red[2]+red[3]);
  }
}

// ---------------- fused Sinkhorn: 2 phases / 2 barriers, row-K in registers ----------------
// Row phase: thread t's 64 K elements (row r_=t&255, quarter p_=t>>8) live in 8 uint4
// VGPRs loaded ONCE; dot product uses 4 independent accumulators (chain depth 16, not 64).
// Col/output phases read the LDS copy (they need K^T access).
#define SINK_DYN_LDS 131072
__global__ __launch_bounds__(1024, 1) void k_sinkhorn_fused(
    const u16* __restrict__ Mbf, const float* __restrict__ muL,
    const float* __restrict__ nuL, u16* __restrict__ Gn, float* __restrict__ accp)
{
  extern __shared__ u16 Ks[];                        // 256x256 bf16, swizzled
  __shared__ __align__(16) float partA[1024];        // row partials (4 per row)
  __shared__ __align__(16) float partB[4096];        // col strip partials (16 x 256)
  __shared__ __align__(16) float svw[1024];          // wave-private v scratch / epilogue row partials
  __shared__ __align__(16) float smu_s[256], snu_s[256], sv_ep[256];
  __shared__ float red[16];

  const int b = blockIdx.x;
  const int t = threadIdx.x;
  const u16* Mb = Mbf + (size_t)b*NN*NN;

  #pragma unroll
  for(int i=0;i<16;i++){
    int e = (i*1024 + t)*4;
    int r = e>>8, c = e&255;
    ushort4 mv = *(const ushort4*)(Mb + e);
    ushort4 o;
    o.x = f2bf(exp2f(-C2LOG*bf2f(mv.x)));
    o.y = f2bf(exp2f(-C2LOG*bf2f(mv.y)));
    o.z = f2bf(exp2f(-C2LOG*bf2f(mv.z)));
    o.w = f2bf(exp2f(-C2LOG*bf2f(mv.w)));
    *(ushort4*)(Ks + LIDX(r,c)) = o;
  }
  if(t < NN){
    smu_s[t] = muL[(size_t)b*NN+t] + 1e-8f;
    snu_s[t] = nuL[(size_t)b*NN+t] + 1e-8f;
  }
  __syncthreads();

  const int w = t>>6, l = t&63;
  const int r_ = t & 255, p_ = t >> 8;     // row-phase mapping
  const int rw = (w<<4) + (l&15);          // col-phase strip row
  const int cl = (p_<<6) + l;              // this lane's v column
  float* svslot = svw + (w<<6);

  // hoist this thread's K row-quarter into registers (one-time)
  uint4 kreg[8];
  #pragma unroll
  for(int jj=0;jj<8;jj++)
    kreg[jj] = *(const uint4*)(Ks + LIDX(r_, (p_<<6)+(jj<<3)));

  #pragma unroll 1
  for(int it=0; it<21; it++){
    // ---- row phase: S_r = sum_c K[r,c] * v[c], v inline from partB ----
    float vl;
    if(it==0){ vl = 1.f; }
    else {
      float t0=0.f,t1=0.f,t2=0.f,t3=0.f;
      #pragma unroll
      for(int ww=0; ww<4; ww++){
        t0 += partB[((ww*4+0)<<8) + cl];
        t1 += partB[((ww*4+1)<<8) + cl];
        t2 += partB[((ww*4+2)<<8) + cl];
        t3 += partB[((ww*4+3)<<8) + cl];
      }
      vl = snu_s[cl] / ((t0+t1)+(t2+t3));
    }
    svslot[l] = vl;
    if(it==20 && (w&3)==0) sv_ep[cl] = vl;   // final v for the output phase
    float s0=0.f, s1=0.f, s2=0.f, s3=0.f;
    #pragma unroll
    for(int jj=0;jj<8;jj++){
      uint4 kv = kreg[jj];
      float4 va = *(const float4*)(svslot + (jj<<3));
      float4 vb = *(const float4*)(svslot + (jj<<3) + 4);
      s0 = fmaf(__uint_as_float(kv.x<<16),           va.x, s0);
      s1 = fmaf(__uint_as_float(kv.x & 0xffff0000u), va.y, s1);
      s2 = fmaf(__uint_as_float(kv.y<<16),           va.z, s2);
      s3 = fmaf(__uint_as_float(kv.y & 0xffff0000u), va.w, s3);
      s0 = fmaf(__uint_as_float(kv.z<<16),           vb.x, s0);
      s1 = fmaf(__uint_as_float(kv.z & 0xffff0000u), vb.y, s1);
      s2 = fmaf(__uint_as_float(kv.w<<16),           vb.z, s2);
      s3 = fmaf(__uint_as_float(kv.w & 0xffff0000u), vb.w, s3);
    }
    float sacc = (s0+s1)+(s2+s3);
    if(it==20) svw[t] = sacc;   // epilogue row sums (wave-private slot, reads done)
    else       partA[t] = sacc;
    __syncthreads();
    if(it==20) break;

    // ---- col phase: T_c = sum_r K[r,c] * u[r], u inline from partA ----
    float S = (partA[rw] + partA[256+rw]) + (partA[512+rw] + partA[768+rw]);
    float ul = smu_s[rw] / S;
    float cs0=0.f,cs1=0.f,cs2=0.f,cs3=0.f;
    #pragma unroll
    for(int rr=0; rr<16; rr++){
      float ur = rdlane(ul, rr);
      ushort4 kv = *(const ushort4*)(Ks + LIDX((w<<4)+rr, l<<2));
      cs0 = fmaf(bf2f(kv.x), ur, cs0);
      cs1 = fmaf(bf2f(kv.y), ur, cs1);
      cs2 = fmaf(bf2f(kv.z), ur, cs2);
      cs3 = fmaf(bf2f(kv.w), ur, cs3);
    }
    float4 o; o.x=cs0; o.y=cs1; o.z=cs2; o.w=cs3;
    *(float4*)(partB + (w<<8) + (l<<2)) = o;
    __syncthreads();
  }

  // ---- output phase (strip-shaped): Gamma, Gn, feat loss ----
  // partA holds (K v_19) row sums -> u_20; svw holds (K v_20) row sums.
  float Sold = (partA[rw] + partA[256+rw]) + (partA[512+rw] + partA[768+rw]);
  float ul   = smu_s[rw] / Sold;
  float Snew = (svw[rw] + svw[256+rw]) + (svw[512+rw] + svw[768+rw]);
  float invl = 1.f / (ul*Snew + 1e-8f);

  u16* Gb = Gn + (size_t)b*NN*NN;
  const float IC = -1.f/C2LOG;
  float4 v4 = *(const float4*)(sv_ep + (l<<2));
  float fl = 0.f;
  #pragma unroll
  for(int rr=0; rr<16; rr++){
    int r = (w<<4) + rr;
    float ur  = rdlane(ul, rr);
    float inv = rdlane(invl, rr);
    ushort4 kv = *(const ushort4*)(Ks + LIDX(r, l<<2));
    float k0=bf2f(kv.x), k1=bf2f(kv.y), k2=bf2f(kv.z), k3=bf2f(kv.w);
    float g0=ur*k0*v4.x, g1=ur*k1*v4.y, g2=ur*k2*v4.z, g3=ur*k3*v4.w;
    fl += g0*(__log2f(k0)*IC) + g1*(__log2f(k1)*IC)
        + g2*(__log2f(k2)*IC) + g3*(__log2f(k3)*IC);
    ushort4 o;
    o.x=f2bf(g0*inv); o.y=f2bf(g1*inv); o.z=f2bf(g2*inv); o.w=f2bf(g3*inv);
    *(ushort4*)(Gb + (size_t)r*NN + (l<<2)) = o;
  }
  fl = wred_sum(fl);
  if(l==0) red[w] = fl;
  __syncthreads();
  if(t==0){
    float s=0.f;
    #pragma unroll
    for(int i=0;i<16;i++) s+=red[i];
    atomicAdd(accp+5, s);
  }
}

__global__ void k_final(const float* __restrict__ acc, float* __restrict__ out){
  out[0] = acc[0]
         + 20.f*acc[3]*(1.f/8128.f)
         + 40.f*acc[4]*(1.f/2048256.f)
         + 0.25f*(acc[5]+acc[6])*(1.f/64.f);
}

// ---------------- host ----------------
extern "C" void kernel_launch(void* const* d_in, const int* in_sizes, int n_in,
                              void* d_out, int out_size, void* d_ws, size_t ws_size,
                              hipStream_t stream) {
  const float* s_q_reps   = (const float*)d_in[0];
  const float* s_p_reps   = (const float*)d_in[1];
  const float* t_q_reps   = (const float*)d_in[2];
  const float* t_p_reps   = (const float*)d_in[3];
  const float* s_q_states = (const float*)d_in[4];
  const float* s_p_states = (const float*)d_in[5];
  const float* t_q_states = (const float*)d_in[6];
  const float* t_p_states = (const float*)d_in[7];
  const float* proj_w     = (const float*)d_in[8];
  const float* proj_b     = (const float*)d_in[9];
  float* ws = (float*)d_ws;
  float* acc = ws + OFF_ACC;
  u16* M_BF   = (u16*)(ws + OFF_MBF);
  u16* ZS_BF  = (u16*)(ws + OFF_ZS_BF);
  u16* ZT_BF  = (u16*)(ws + OFF_ZT_BF);
  u16* WT_BF  = (u16*)(ws + OFF_WT_BF);
  u16* ZSP_BF = (u16*)(ws + OFF_ZSP_BF);
  u16* GN_BF  = (u16*)(ws + OFF_GN_BF);
  u16* CT_BF  = (u16*)(ws + OFF_CT_BF);
  u16* T_BF   = (u16*)(ws + OFF_T_BF);

  hipFuncSetAttribute(reinterpret_cast<const void*>(k_sinkhorn_fused),
                      hipFuncAttributeMaxDynamicSharedMemorySize, SINK_DYN_LDS);
  hipFuncSetAttribute(reinterpret_cast<const void*>(k_rkd_angle_mfma),
                      hipFuncAttributeMaxDynamicSharedMemorySize, RKD_LDS);

  hipMemsetAsync(acc, 0, 16*sizeof(float), stream);

  // ---- Part A ----
  k_l2norm_all<<<384,256,0,stream>>>(s_q_reps, s_p_reps, t_q_reps, t_p_reps, ws);
  k_contrastive2<<<128,512,0,stream>>>(ws, acc);
  k_gram_ds<<<128,128,0,stream>>>(ws+OFF_SQ128, ws+OFF_TQ128, ws+OFF_DS, ws+OFF_DT, acc);
  k_rkd_dist<<<128,128,0,stream>>>(ws+OFF_DS, ws+OFF_DT, acc);
  k_rkd_angle_mfma<<<256,256,RKD_LDS,stream>>>(ws+OFF_SQ128, ws+OFF_TQ128, acc);

  k_wt<<<dim3(HTT/32, HSS/32),dim3(32,8),0,stream>>>(proj_w, WT_BF);

  // ---- Part B phase 1: per-pass GEMMs into doubled buffers ----
  for(int pass=0; pass<2; pass++){
    const float* zs = pass ? s_p_states : s_q_states;
    const float* zt = pass ? t_p_states : t_q_states;
    size_t po  = (size_t)pass*NB*NN*NN;
    size_t pr  = (size_t)pass*ROWS;
    k_cvt_norm<<<ROWS/4,256,0,stream>>>(zs, ZS_BF, ws+OFF_NS, HSS);
    k_cvt_norm<<<ROWS/4,256,0,stream>>>(zt, ZT_BF, ws+OFF_NT, HTT);
    k_saliency2<<<128,256,0,stream>>>(ws+OFF_NS, ws+OFF_NT, ws+OFF_MU+pr, ws+OFF_NU+pr);
    k_mfma<MODE_PROJ><<<dim3(HTT/128, ROWS/128, 1),256,0,stream>>>(
        ZS_BF, HSS, 0, WT_BF, HSS, 0, HSS,
        nullptr, ZSP_BF, HTT, 0,
        nullptr, nullptr, proj_b, nullptr, nullptr, nullptr);
    k_row_norm_bf16<<<ROWS/4,256,0,stream>>>(ZSP_BF, ws+OFF_NSP, HTT);
    // C_s (f32)
    k_mfma<MODE_COST><<<dim3(2,2,NB),256,0,stream>>>(
        ZS_BF, HSS, (long)NN*HSS, ZS_BF, HSS, (long)NN*HSS, HSS,
        ws+OFF_CS+po, nullptr, NN, (long)NN*NN,
        ws+OFF_NS, ws+OFF_NS, nullptr, nullptr, nullptr, nullptr);
    // C_t (bf16)
    k_mfma<MODE_COST><<<dim3(2,2,NB),256,0,stream>>>(
        ZT_BF, HTT, (long)NN*HTT, ZT_BF, HTT, (long)NN*HTT, HTT,
        nullptr, CT_BF+po, NN, (long)NN*NN,
        ws+OFF_NT, ws+OFF_NT, nullptr, nullptr, nullptr, nullptr);
    // M (bf16)
    k_mfma<MODE_COST><<<dim3(2,2,NB),256,0,stream>>>(
        ZSP_BF, HTT, (long)NN*HTT, ZT_BF, HTT, (long)NN*HTT, HTT,
        nullptr, M_BF+po, NN, (long)NN*NN,
        ws+OFF_NSP, ws+OFF_NT, nullptr, nullptr, nullptr, nullptr);
  }

  // ---- Part B phase 2: Sinkhorn (both passes, multiplicative, K in LDS) ----
  k_sinkhorn_fused<<<2*NB,1024,SINK_DYN_LDS,stream>>>(
      M_BF, ws+OFF_MU, ws+OFF_NU, GN_BF, acc);

  // ---- Part B phase 3: T = Gn@Ct, struct loss (batched over both passes) ----
  k_mfma<MODE_PLAIN><<<dim3(2,2,2*NB),256,0,stream>>>(
      GN_BF, NN, (long)NN*NN, CT_BF, NN, (long)NN*NN, NN,
      nullptr, T_BF, NN, (long)NN*NN,
      nullptr, nullptr, nullptr, nullptr, nullptr, nullptr);
  k_mfma<MODE_STRUCT><<<dim3(2,2,2*NB),256,0,stream>>>(
      T_BF, NN, (long)NN*NN, GN_BF, NN, (long)NN*NN, NN,
      nullptr, nullptr, NN, (long)NN*NN,
      nullptr, nullptr, nullptr, ws+OFF_CS, ws+OFF_MU, acc);

  k_final<<<1,1,0,stream>>>(acc, (float*)d_out);
}